// Round 6
// baseline (14777.225 us; speedup 1.0000x reference)
//
#include <hip/hip_runtime.h>
#include <hip/hip_bf16.h>
#include <cstdint>
#include <cstddef>

constexpr int BATCH = 64;
constexpr int SEQ   = 512;
constexpr int DIM   = 256;
constexpr int HID   = 1024;
constexpr int COUT  = 128;
constexpr int KTOT  = DIM + HID;   // 1280
constexpr int NGATE = 4 * HID;     // 4096
constexpr float ATT_SIG_W = 3.0f;

using bf16x8 = __attribute__((ext_vector_type(8))) __bf16;
using f32x4  = __attribute__((ext_vector_type(4))) float;
using u32x4  = __attribute__((ext_vector_type(4))) unsigned int;

__device__ __forceinline__ unsigned short f2bf(float f) {
    union { float f; unsigned u; } v; v.f = f;
    unsigned u = v.u;
    u += 0x7fffu + ((u >> 16) & 1u);
    return (unsigned short)(u >> 16);
}

__device__ __forceinline__ float sigm(float x) { return 1.f / (1.f + __expf(-x)); }

// 16B write-through store (sc0 sc1): payload must be an ext_vector_type (reg quad),
// NOT HIP's uint4 class (aggregate -> "indirect register input" compile error).
__device__ __forceinline__ void store_16B_wt(void* p, u32x4 v) {
    asm volatile("global_store_dwordx4 %0, %1, off sc0 sc1"
                 :: "v"(p), "v"(v) : "memory");
}

// global->LDS direct copy, 16B/lane, sc0|sc1 (aux=17): bypass L1+L2, read coherent L3
#define GLOAD_LDS_COHERENT(gptr, lptr)                                     \
    __builtin_amdgcn_global_load_lds(                                      \
        (const __attribute__((address_space(1))) void*)(gptr),             \
        (__attribute__((address_space(3))) void*)(lptr), 16, 0, 17)

// ---- weight transpose+convert: out[n][k] = bf16( k<DIM ? wi[k][n] : wh[k-DIM][n] )
__global__ void transpose_weights(const float* __restrict__ wi,
                                  const float* __restrict__ wh,
                                  unsigned short* __restrict__ out, int N) {
    __shared__ float tile[64][65];
    int ntiles = N >> 6;
    int kt = blockIdx.x / ntiles;
    int nt = blockIdx.x % ntiles;
    int k0 = kt << 6, n0 = nt << 6;
    int a = threadIdx.x & 63, g = threadIdx.x >> 6;
#pragma unroll
    for (int p = 0; p < 16; ++p) {
        int kr = p * 4 + g;
        int k = k0 + kr;
        const float* src = (k < DIM) ? (wi + (size_t)k * N) : (wh + (size_t)(k - DIM) * N);
        tile[kr][a] = src[n0 + a];
    }
    __syncthreads();
#pragma unroll
    for (int p = 0; p < 16; ++p) {
        int nr = p * 4 + g;
        out[(size_t)(n0 + nr) * KTOT + (k0 + a)] = f2bf(tile[a][nr]);
    }
}

// ---- x [B][T][D] f32 -> xt [T][B][D] bf16
__global__ void transpose_x(const float* __restrict__ x, unsigned short* __restrict__ xt) {
    size_t idx = (size_t)blockIdx.x * blockDim.x + threadIdx.x;
    if (idx >= (size_t)SEQ * BATCH * DIM) return;
    int d = idx % DIM;
    size_t r = idx / DIM;
    int b = r % BATCH;
    int t = r / BATCH;
    xt[idx] = f2bf(x[((size_t)b * SEQ + t) * DIM + d]);
}

// ---- pack LSTM weights into per-(colgroup, khalf) MFMA fragment order.
__global__ void pack_lstm(const unsigned short* __restrict__ WT,
                          unsigned short* __restrict__ out) {
    int cg = blockIdx.x >> 1, kh = blockIdx.x & 1;
    size_t base = (size_t)blockIdx.x * 20480;
#pragma unroll
    for (int j = 0; j < 80; ++j) {
        int idx = threadIdx.x * 80 + j;
        int frag = idx >> 9;
        int rem = idx & 511;
        int lane = rem >> 3, e = rem & 7;
        int nt = frag / 20, ksl = frag % 20;
        int p = nt * 16 + (lane & 15);
        int origcol = (p >> 3) * 1024 + cg * 8 + (p & 7);
        int k = kh * 640 + ksl * 32 + ((lane >> 4) & 3) * 8 + e;
        out[base + idx] = WT[(size_t)origcol * KTOT + k];
    }
}

// ---- pack TAGM weights: region (cg,kh): 20 frags x 1024B; col = cg*16+(lane&15)
__global__ void pack_tagm(const unsigned short* __restrict__ WT,
                          unsigned short* __restrict__ out) {
    int cg = blockIdx.x >> 1, kh = blockIdx.x & 1;
    size_t base = (size_t)blockIdx.x * 10240;
#pragma unroll
    for (int j = 0; j < 40; ++j) {
        int idx = threadIdx.x * 40 + j;
        int ksl = idx >> 9;
        int rem = idx & 511;
        int lane = rem >> 3, e = rem & 7;
        int origcol = cg * 16 + (lane & 15);
        int k = kh * 640 + ksl * 32 + ((lane >> 4) & 3) * 8 + e;
        out[base + idx] = WT[(size_t)origcol * KTOT + k];
    }
}

// ---- LIGHT per-step barrier: no cache-maintenance fences (h traffic is WT + L2-bypass)
__device__ __forceinline__ void flag_light(unsigned* flags, int base, int cnt,
                                           int myidx, unsigned epoch) {
    asm volatile("s_waitcnt vmcnt(0)" ::: "memory");  // each wave drains its own WT stores
    __syncthreads();
    if (threadIdx.x == 0)
        __hip_atomic_store(flags + myidx, epoch, __ATOMIC_RELAXED, __HIP_MEMORY_SCOPE_AGENT);
    if (threadIdx.x < 64) {
        for (;;) {
            bool ok = true;
            for (int j = (int)threadIdx.x; j < cnt; j += 64)
                ok &= (__hip_atomic_load(flags + base + j, __ATOMIC_RELAXED,
                                         __HIP_MEMORY_SCOPE_AGENT) >= epoch);
            if (__all(ok)) break;
            __builtin_amdgcn_s_sleep(1);
        }
    }
    __syncthreads();
}

// ---- HEAVY barrier (phase boundaries only): full release/acquire fences
__device__ __forceinline__ void flag_barrier(unsigned* flags, int base, int cnt,
                                             int myidx, unsigned epoch) {
    __syncthreads();
    if (threadIdx.x == 0) {
        __builtin_amdgcn_fence(__ATOMIC_RELEASE, "agent");   // wbl2
        __hip_atomic_store(flags + myidx, epoch, __ATOMIC_RELAXED, __HIP_MEMORY_SCOPE_AGENT);
    }
    if (threadIdx.x < 64) {
        for (;;) {
            bool ok = true;
            for (int j = (int)threadIdx.x; j < cnt; j += 64)
                ok &= (__hip_atomic_load(flags + base + j, __ATOMIC_RELAXED,
                                         __HIP_MEMORY_SCOPE_AGENT) >= epoch);
            if (__all(ok)) break;
            __builtin_amdgcn_s_sleep(1);
        }
        if (threadIdx.x == 0)
            __builtin_amdgcn_fence(__ATOMIC_ACQUIRE, "agent");   // inv
    }
    __syncthreads();
}

// ======== the persistent fused kernel ========
// grid 256 x 256thr; LDS 142KiB -> 1 block/CU -> all blocks co-resident.
// LSTM: block = (dir = bid&1, cg = bid>>1 : 8 h-cols x 4 gates). wave = (mh, kh).
// h global layout is BLOCKED: h[cg][row][8cols] (1KB contiguous per block) so each
// block's per-step write is 16 full 64B lines (no cross-block partial-line RMW).
// TAGM (bid<64): 16 h-cols/block, h layout [tb][row][16cols] (2KB/block).
__global__ __launch_bounds__(256)
void tagm_fused(const unsigned short* __restrict__ xt,
                const unsigned short* __restrict__ Wfp,
                const unsigned short* __restrict__ Wbp,
                const unsigned short* __restrict__ Wtp,
                const float* __restrict__ bias_f, const float* __restrict__ bias_b,
                const float* __restrict__ attw, const float* __restrict__ att_fc_b,
                const float* __restrict__ i2h_b, const float* __restrict__ h2h_b,
                const float* __restrict__ fc_w, const float* __restrict__ fc_b,
                unsigned short* __restrict__ h_lstm,  // [2 dir][2 buf] x 128KB blocked
                unsigned short* __restrict__ h_tagm,  // [2 buf] x 128KB blocked
                float* __restrict__ h_f32,            // [64][1024]
                float* __restrict__ att_part,         // [256 blk][512*64] f32 (aliases Wfp/Wbp!)
                unsigned* __restrict__ flags,         // [640]
                float* __restrict__ out) {
    extern __shared__ char smem[];                   // [0,131072): h stage (swizzled)
    char* dumpbase = smem + 131072;                  // 8 KB acc dump
    float* auxf = (float*)(smem + 131072 + 8192);    // 4 KB: LSTM c / TAGM h master
    unsigned short* hscr = (unsigned short*)(smem + 131072 + 8192 + 4096);  // 2 KB h scratch

    int tid = threadIdx.x;
    int wave = tid >> 6, lane = tid & 63;
    int bid = blockIdx.x;
    int dir = bid & 1, cg = bid >> 1;
    int mh = wave >> 1, kh = wave & 1;
    int q = lane >> 4, c15 = lane & 15;

    // ---- LSTM weight fragments -> registers
    bf16x8 wreg[40];
    {
        const unsigned short* wp = (dir ? Wbp : Wfp) + (size_t)(cg * 2 + kh) * 20480;
#pragma unroll
        for (int f = 0; f < 40; ++f)
            wreg[f] = *(const bf16x8*)(wp + f * 512 + lane * 8);
    }
    int hc = lane & 7;
    int colE = cg * 8 + hc;
    const float* bias = dir ? bias_b : bias_f;
    float b_ii = bias[colE], b_ff = bias[HID + colE];
    float b_gg = bias[2 * HID + colE], b_oo = bias[3 * HID + colE];
    float attw_l = attw[dir * HID + colE];

    for (int i = tid; i < 512; i += 256) auxf[i] = 0.f;   // c = 0

    // weights in regs (vmcnt-drained by flag_light) before att_part may clobber Wfp/Wbp
    flag_light(flags, 256, 256, 256 + bid, 1u);

    // =============== LSTM loop ===============
    for (int t = 0; t < SEQ; ++t) {
        int tx = dir ? (SEQ - 1 - t) : t;
        {   // stage h_prev -> LDS; global is blocked [cg][row][16B], src pre-swizzled
            const char* hsrc = (const char*)h_lstm + (size_t)(dir * 2 + (t & 1)) * 131072;
            char* lbase = smem + (size_t)(tid & 192) * 16;
#pragma unroll
            for (int i = 0; i < 32; ++i) {
                int s = i * 256 + tid;                 // linear 16B-chunk index
                int row = s >> 7;
                int c16 = (s & 127) ^ (row & 7);       // involution: swizzled col-chunk
                GLOAD_LDS_COHERENT(hsrc + (size_t)(c16 * 1024 + row * 16),
                                   lbase + (size_t)i * 4096);
            }
        }
        // prefetch x fragments (normal cached loads; xt is read-only, L2-resident)
        const unsigned short* xrow = xt + (size_t)tx * BATCH * DIM;
        bf16x8 xa[16];
        if (kh == 0) {
#pragma unroll
            for (int ksl = 0; ksl < 8; ++ksl)
#pragma unroll
                for (int mt = 0; mt < 2; ++mt) {
                    int row = mh * 32 + mt * 16 + c15;
                    xa[ksl * 2 + mt] = *(const bf16x8*)(xrow + row * DIM + ksl * 32 + q * 8);
                }
        }
        __syncthreads();   // drains global_load_lds (vmcnt) + xa, then barrier

        f32x4 acc[2][2] = {};
#pragma unroll
        for (int ksl = 0; ksl < 20; ++ksl) {
            int kk = kh * 640 + ksl * 32 + q * 8;
#pragma unroll
            for (int mt = 0; mt < 2; ++mt) {
                int row = mh * 32 + mt * 16 + c15;
                bf16x8 a;
                if (kh == 0 && ksl < 8) {
                    a = xa[ksl * 2 + mt];
                } else {
                    unsigned off = (unsigned)(row * 2048 + (kk - 256) * 2) ^ ((row & 7) << 4);
                    a = *(const bf16x8*)(smem + off);
                }
                acc[mt][0] = __builtin_amdgcn_mfma_f32_16x16x32_bf16(a, wreg[ksl],      acc[mt][0], 0, 0, 0);
                acc[mt][1] = __builtin_amdgcn_mfma_f32_16x16x32_bf16(a, wreg[20 + ksl], acc[mt][1], 0, 0, 0);
            }
        }
        if (kh == 1) {   // k-half-1 waves dump partials
            float* dp = (float*)(dumpbase + mh * 4096);
#pragma unroll
            for (int mt = 0; mt < 2; ++mt)
#pragma unroll
                for (int nt = 0; nt < 2; ++nt)
                    *(f32x4*)(dp + ((mt * 2 + nt) * 64 + lane) * 4) = acc[mt][nt];
        }
        __syncthreads();
        if (kh == 0) {   // reduce + gates + state update (waves 0,2 in parallel)
            const float* dp = (const float*)(dumpbase + mh * 4096);
            bool low = (lane & 8) == 0;
#pragma unroll
            for (int mt = 0; mt < 2; ++mt) {
                f32x4 g0 = acc[mt][0] + *(const f32x4*)(dp + ((mt * 2 + 0) * 64 + lane) * 4);
                f32x4 g1 = acc[mt][1] + *(const f32x4*)(dp + ((mt * 2 + 1) * 64 + lane) * 4);
                f32x4 av4;
#pragma unroll
                for (int r = 0; r < 4; ++r) {
                    float fo0 = __shfl(g0[r], lane ^ 8);   // f gate from partner lane
                    float fo1 = __shfl(g1[r], lane ^ 8);   // o gate from partner lane
                    int row = mh * 32 + mt * 16 + q * 4 + r;
                    float si = sigm(g0[r] + b_ii);
                    float sf = sigm(fo0 + b_ff);
                    float tg = tanhf(g1[r] + b_gg);
                    float so = sigm(fo1 + b_oo);
                    float cprev = auxf[row * 8 + hc];
                    float cn = sf * cprev + si * tg;
                    float hn = so * tanhf(cn);
                    float av = low ? hn * attw_l : 0.f;
                    av += __shfl_xor(av, 1); av += __shfl_xor(av, 2); av += __shfl_xor(av, 4);
                    av4[r] = av;
                    if (low) {
                        auxf[row * 8 + hc] = cn;
                        hscr[row * 8 + hc] = f2bf(hn);     // LDS transpose staging
                    }
                }
                if (c15 == 0)
                    *(f32x4*)(att_part + (size_t)bid * 32768 + tx * 64 + (mh * 32 + mt * 16 + q * 4)) = av4;
            }
        }
        __syncthreads();   // hscr complete
        if (tid < 64) {    // 16B/thread -> block's contiguous 1KB region: 16 full lines
            u32x4 v = *(const u32x4*)(hscr + tid * 8);
            char* dst = (char*)h_lstm + (size_t)(dir * 2 + ((t + 1) & 1)) * 131072
                        + (size_t)cg * 1024 + tid * 16;
            store_16B_wt(dst, v);
        }
        flag_light(flags, dir * 128, 128, dir * 128 + cg, (unsigned)(t + 1));
    }

    // =============== attention finalize ===============
    flag_barrier(flags, 256, 256, 256 + bid, 2u);   // heavy: att_part was cached-written
    {
        int i = tid & 127, half = tid >> 7;
        int item = bid * 128 + i;               // = t*64 + row
        int tt = item >> 6, row = item & 63;
        float s = 0.f;
        const float* p = att_part + (size_t)half * 128 * 32768 + item;
        for (int blk = 0; blk < 128; ++blk)
            s += p[(size_t)blk * 32768];
        float* red = (float*)dumpbase;
        if (half) red[i] = s;
        __syncthreads();
        if (!half)
            out[BATCH * COUT + row * SEQ + tt] = sigm(ATT_SIG_W * (s + red[i] + att_fc_b[0]));
    }
    flag_barrier(flags, 256, 256, 256 + bid, 3u);   // heavy: att out cached-written
    if (bid >= 64) return;

    // =============== TAGM loop (64 blocks) ===============
    bf16x8 wt[20];
    {
        const unsigned short* wp = Wtp + (size_t)(bid * 2 + kh) * 10240;
#pragma unroll
        for (int f = 0; f < 20; ++f)
            wt[f] = *(const bf16x8*)(wp + f * 512 + lane * 8);
    }
    int colT = bid * 16 + c15;
    float bbT = i2h_b[colT] + h2h_b[colT];
    for (int i = tid; i < 1024; i += 256) auxf[i] = 0.f;   // h master = 0
    __syncthreads();
    const float* attd = out + BATCH * COUT;

    for (int t = 0; t < SEQ; ++t) {
        {   // stage: global blocked [tb][row][32B] -> LDS linear rows, src pre-swizzled
            const char* hsrc = (const char*)h_tagm + (size_t)(t & 1) * 131072;
            char* lbase = smem + (size_t)(tid & 192) * 16;
#pragma unroll
            for (int i = 0; i < 32; ++i) {
                int s = i * 256 + tid;
                int row = s >> 7;
                int c16 = (s & 127) ^ (row & 7);
                GLOAD_LDS_COHERENT(hsrc + (size_t)((c16 >> 1) * 2048 + row * 32 + (c16 & 1) * 16),
                                   lbase + (size_t)i * 4096);
            }
        }
        const unsigned short* xrow = xt + (size_t)t * BATCH * DIM;
        bf16x8 xa[16];
        if (kh == 0) {
#pragma unroll
            for (int ksl = 0; ksl < 8; ++ksl)
#pragma unroll
                for (int mt = 0; mt < 2; ++mt) {
                    int row = mh * 32 + mt * 16 + c15;
                    xa[ksl * 2 + mt] = *(const bf16x8*)(xrow + row * DIM + ksl * 32 + q * 8);
                }
        }
        __syncthreads();
        f32x4 acc[2] = {};
#pragma unroll
        for (int ksl = 0; ksl < 20; ++ksl) {
            int kk = kh * 640 + ksl * 32 + q * 8;
#pragma unroll
            for (int mt = 0; mt < 2; ++mt) {
                int row = mh * 32 + mt * 16 + c15;
                bf16x8 a;
                if (kh == 0 && ksl < 8) {
                    a = xa[ksl * 2 + mt];
                } else {
                    unsigned off = (unsigned)(row * 2048 + (kk - 256) * 2) ^ ((row & 7) << 4);
                    a = *(const bf16x8*)(smem + off);
                }
                acc[mt] = __builtin_amdgcn_mfma_f32_16x16x32_bf16(a, wt[ksl], acc[mt], 0, 0, 0);
            }
        }
        if (kh == 1) {
            float* dp = (float*)(dumpbase + mh * 2048);
            *(f32x4*)(dp + (0 * 64 + lane) * 4) = acc[0];
            *(f32x4*)(dp + (1 * 64 + lane) * 4) = acc[1];
        }
        __syncthreads();
        if (kh == 0) {
            const float* dp = (const float*)(dumpbase + mh * 2048);
#pragma unroll
            for (int mt = 0; mt < 2; ++mt) {
                f32x4 g = acc[mt] + *(const f32x4*)(dp + (mt * 64 + lane) * 4);
#pragma unroll
                for (int r = 0; r < 4; ++r) {
                    int row = mh * 32 + mt * 16 + q * 4 + r;
                    float cand = g[r] + bbT;
                    cand = cand > 0.f ? cand : 0.f;
                    float a = attd[row * SEQ + t];
                    float hold = auxf[row * 16 + c15];
                    float hn = a * cand + (1.f - a) * hold;
                    auxf[row * 16 + c15] = hn;
                    hscr[row * 16 + c15] = f2bf(hn);     // LDS transpose staging
                }
            }
        }
        __syncthreads();   // hscr complete
        if (tid < 128) {   // 16B/thread -> block's contiguous 2KB region: 32 full lines
            u32x4 v = *(const u32x4*)(hscr + tid * 8);
            char* dst = (char*)h_tagm + (size_t)((t + 1) & 1) * 131072
                        + (size_t)bid * 2048 + tid * 16;
            store_16B_wt(dst, v);
        }
        flag_light(flags, 512, 64, 512 + bid, (unsigned)(t + 1));
    }

    // dump final h (f32) for FC
    for (int i = tid; i < 1024; i += 256) {
        int row = i >> 4, cl = i & 15;
        h_f32[row * HID + bid * 16 + cl] = auxf[i];
    }
    flag_barrier(flags, 576, 64, 576 + bid, 1u);   // heavy: h_f32 cached-written

    // =============== FC: out[b][c], block = batch row ===============
    {
        float* fcp = (float*)dumpbase;   // [2][128]
        int c = tid & 127, half = tid >> 7;
        const float* hrow = h_f32 + (size_t)bid * HID;
        float s = 0.f;
        for (int k = half * 512; k < half * 512 + 512; ++k)
            s += hrow[k] * fc_w[(size_t)k * COUT + c];
        fcp[half * 128 + c] = s;
        __syncthreads();
        if (tid < 128)
            out[bid * COUT + tid] = fcp[tid] + fcp[128 + tid] + fc_b[tid];
    }
}

extern "C" void kernel_launch(void* const* d_in, const int* in_sizes, int n_in,
                              void* d_out, int out_size, void* d_ws, size_t ws_size,
                              hipStream_t stream) {
    const float* x          = (const float*)d_in[0];
    const float* i2h_w      = (const float*)d_in[1];
    const float* i2h_b      = (const float*)d_in[2];
    const float* h2h_w      = (const float*)d_in[3];
    const float* h2h_b      = (const float*)d_in[4];
    const float* fc_w       = (const float*)d_in[5];
    const float* fc_b       = (const float*)d_in[6];
    const float* att_wi_fwd = (const float*)d_in[7];
    const float* att_wh_fwd = (const float*)d_in[8];
    const float* att_b_fwd  = (const float*)d_in[9];
    const float* att_wi_bwd = (const float*)d_in[10];
    const float* att_wh_bwd = (const float*)d_in[11];
    const float* att_b_bwd  = (const float*)d_in[12];
    const float* att_fc_w   = (const float*)d_in[13];
    const float* att_fc_b   = (const float*)d_in[14];
    float* out = (float*)d_out;

    char* ws = (char*)d_ws;
    // setup-phase (transposed f32->bf16 weights; dead after pack_* consume them)
    unsigned short* WfT = (unsigned short*)(ws + 0);          // 10485760
    unsigned short* WbT = (unsigned short*)(ws + 10485760);   // 10485760
    unsigned short* WtT = (unsigned short*)(ws + 20971520);   // 2621440 -> 23592960
    // packed fragment weights
    unsigned short* Wfp = (unsigned short*)(ws + 23592960);   // 10485760
    unsigned short* Wbp = (unsigned short*)(ws + 34078720);   // 10485760 -> 44564480
    unsigned short* Wtp = (unsigned short*)(ws + 17829888);   // 2621440 -> 20451328 (survives)
    // runtime region
    unsigned short* xtb    = (unsigned short*)(ws + 0);        // 16777216
    unsigned short* h_lstm = (unsigned short*)(ws + 16777216); // 524288
    unsigned short* h_tagm = (unsigned short*)(ws + 17301504); // 262144
    float*          h_f32  = (float*)(ws + 17563648);          // 262144
    unsigned*       flags  = (unsigned*)(ws + 17825792);       // 4096 -> 17829888
    // att_part ALIASES Wfp/Wbp + tail (weights are in registers after epoch-1 barrier)
    float*          att_part = (float*)(ws + 23592960);        // 256*32768*4 = 33554432 -> 57147392

    transpose_weights<<<20 * (NGATE / 64), 256, 0, stream>>>(att_wi_fwd, att_wh_fwd, WfT, NGATE);
    transpose_weights<<<20 * (NGATE / 64), 256, 0, stream>>>(att_wi_bwd, att_wh_bwd, WbT, NGATE);
    transpose_weights<<<20 * (HID / 64), 256, 0, stream>>>(i2h_w, h2h_w, WtT, HID);
    pack_lstm<<<256, 256, 0, stream>>>(WfT, Wfp);
    pack_lstm<<<256, 256, 0, stream>>>(WbT, Wbp);   // frees WbT; Wtp (17.8-20.5MB) written next
    pack_tagm<<<128, 256, 0, stream>>>(WtT, Wtp);
    transpose_x<<<(SEQ * BATCH * DIM + 255) / 256, 256, 0, stream>>>(x, xtb);
    // zero recurrent state + flags every call (replays mutate them)
    (void)hipMemsetAsync(ws + 16777216, 0, 17829888 - 16777216, stream);

    static const int SMEM_BYTES = 131072 + 8192 + 4096 + 2048;   // 145408
    (void)hipFuncSetAttribute(reinterpret_cast<const void*>(tagm_fused),
                              hipFuncAttributeMaxDynamicSharedMemorySize, SMEM_BYTES);
    tagm_fused<<<256, 256, SMEM_BYTES, stream>>>(
        xtb, Wfp, Wbp, Wtp, att_b_fwd, att_b_bwd, att_fc_w, att_fc_b,
        i2h_b, h2h_b, fc_w, fc_b, h_lstm, h_tagm, h_f32, att_part, flags, out);
}

// Round 7
// 13150.868 us; speedup vs baseline: 1.1237x; 1.1237x over previous
//
#include <hip/hip_runtime.h>
#include <hip/hip_bf16.h>
#include <cstdint>
#include <cstddef>

constexpr int BATCH = 64;
constexpr int SEQ   = 512;
constexpr int DIM   = 256;
constexpr int HID   = 1024;
constexpr int COUT  = 128;
constexpr int KTOT  = DIM + HID;   // 1280
constexpr int NGATE = 4 * HID;     // 4096
constexpr float ATT_SIG_W = 3.0f;

using bf16x8 = __attribute__((ext_vector_type(8))) __bf16;
using f32x4  = __attribute__((ext_vector_type(4))) float;
using u32x4  = __attribute__((ext_vector_type(4))) unsigned int;

__device__ __forceinline__ unsigned short f2bf(float f) {
    union { float f; unsigned u; } v; v.f = f;
    unsigned u = v.u;
    u += 0x7fffu + ((u >> 16) & 1u);
    return (unsigned short)(u >> 16);
}

__device__ __forceinline__ float sigm(float x) { return 1.f / (1.f + __expf(-x)); }

// 16B write-through store (sc0 sc1); payload must be ext_vector_type (reg quad)
__device__ __forceinline__ void store_16B_wt(void* p, u32x4 v) {
    asm volatile("global_store_dwordx4 %0, %1, off sc0 sc1"
                 :: "v"(p), "v"(v) : "memory");
}

// global->LDS direct copy, 16B/lane, sc0|sc1 (aux=17): bypass L1+L2, read coherent L3
#define GLOAD_LDS_COHERENT(gptr, lptr)                                     \
    __builtin_amdgcn_global_load_lds(                                      \
        (const __attribute__((address_space(1))) void*)(gptr),             \
        (__attribute__((address_space(3))) void*)(lptr), 16, 0, 17)

// ---- weight transpose+convert: out[n][k] = bf16( k<DIM ? wi[k][n] : wh[k-DIM][n] )
__global__ void transpose_weights(const float* __restrict__ wi,
                                  const float* __restrict__ wh,
                                  unsigned short* __restrict__ out, int N) {
    __shared__ float tile[64][65];
    int ntiles = N >> 6;
    int kt = blockIdx.x / ntiles;
    int nt = blockIdx.x % ntiles;
    int k0 = kt << 6, n0 = nt << 6;
    int a = threadIdx.x & 63, g = threadIdx.x >> 6;
#pragma unroll
    for (int p = 0; p < 16; ++p) {
        int kr = p * 4 + g;
        int k = k0 + kr;
        const float* src = (k < DIM) ? (wi + (size_t)k * N) : (wh + (size_t)(k - DIM) * N);
        tile[kr][a] = src[n0 + a];
    }
    __syncthreads();
#pragma unroll
    for (int p = 0; p < 16; ++p) {
        int nr = p * 4 + g;
        out[(size_t)(n0 + nr) * KTOT + (k0 + a)] = f2bf(tile[a][nr]);
    }
}

// ---- x [B][T][D] f32 -> xt [T][B][D] bf16
__global__ void transpose_x(const float* __restrict__ x, unsigned short* __restrict__ xt) {
    size_t idx = (size_t)blockIdx.x * blockDim.x + threadIdx.x;
    if (idx >= (size_t)SEQ * BATCH * DIM) return;
    int d = idx % DIM;
    size_t r = idx / DIM;
    int b = r % BATCH;
    int t = r / BATCH;
    xt[idx] = f2bf(x[((size_t)b * SEQ + t) * DIM + d]);
}

// ---- pack LSTM weights into per-(colgroup, khalf) MFMA fragment order.
__global__ void pack_lstm(const unsigned short* __restrict__ WT,
                          unsigned short* __restrict__ out) {
    int cg = blockIdx.x >> 1, kh = blockIdx.x & 1;
    size_t base = (size_t)blockIdx.x * 20480;
#pragma unroll
    for (int j = 0; j < 80; ++j) {
        int idx = threadIdx.x * 80 + j;
        int frag = idx >> 9;
        int rem = idx & 511;
        int lane = rem >> 3, e = rem & 7;
        int nt = frag / 20, ksl = frag % 20;
        int p = nt * 16 + (lane & 15);
        int origcol = (p >> 3) * 1024 + cg * 8 + (p & 7);
        int k = kh * 640 + ksl * 32 + ((lane >> 4) & 3) * 8 + e;
        out[base + idx] = WT[(size_t)origcol * KTOT + k];
    }
}

// ---- pack TAGM weights: region (cg,kh): 20 frags x 1024B; col = cg*16+(lane&15)
__global__ void pack_tagm(const unsigned short* __restrict__ WT,
                          unsigned short* __restrict__ out) {
    int cg = blockIdx.x >> 1, kh = blockIdx.x & 1;
    size_t base = (size_t)blockIdx.x * 10240;
#pragma unroll
    for (int j = 0; j < 40; ++j) {
        int idx = threadIdx.x * 40 + j;
        int ksl = idx >> 9;
        int rem = idx & 511;
        int lane = rem >> 3, e = rem & 7;
        int origcol = cg * 16 + (lane & 15);
        int k = kh * 640 + ksl * 32 + ((lane >> 4) & 3) * 8 + e;
        out[base + idx] = WT[(size_t)origcol * KTOT + k];
    }
}

// ---- LIGHT per-step barrier: no cache-maintenance fences (h is WT + L2-bypass)
__device__ __forceinline__ void flag_light(unsigned* flags, int base, int cnt,
                                           int myidx, unsigned epoch) {
    asm volatile("s_waitcnt vmcnt(0)" ::: "memory");  // drain own WT stores
    __syncthreads();
    if (threadIdx.x == 0)
        __hip_atomic_store(flags + myidx, epoch, __ATOMIC_RELAXED, __HIP_MEMORY_SCOPE_AGENT);
    if (threadIdx.x < 64) {
        for (;;) {
            bool ok = true;
            for (int j = (int)threadIdx.x; j < cnt; j += 64)
                ok &= (__hip_atomic_load(flags + base + j, __ATOMIC_RELAXED,
                                         __HIP_MEMORY_SCOPE_AGENT) >= epoch);
            if (__all(ok)) break;
            __builtin_amdgcn_s_sleep(1);
        }
    }
    __syncthreads();
}

// ---- HEAVY barrier (phase boundaries only): full release/acquire fences
__device__ __forceinline__ void flag_barrier(unsigned* flags, int base, int cnt,
                                             int myidx, unsigned epoch) {
    __syncthreads();
    if (threadIdx.x == 0) {
        __builtin_amdgcn_fence(__ATOMIC_RELEASE, "agent");   // wbl2
        __hip_atomic_store(flags + myidx, epoch, __ATOMIC_RELAXED, __HIP_MEMORY_SCOPE_AGENT);
    }
    if (threadIdx.x < 64) {
        for (;;) {
            bool ok = true;
            for (int j = (int)threadIdx.x; j < cnt; j += 64)
                ok &= (__hip_atomic_load(flags + base + j, __ATOMIC_RELAXED,
                                         __HIP_MEMORY_SCOPE_AGENT) >= epoch);
            if (__all(ok)) break;
            __builtin_amdgcn_s_sleep(1);
        }
        if (threadIdx.x == 0)
            __builtin_amdgcn_fence(__ATOMIC_ACQUIRE, "agent");   // inv
    }
    __syncthreads();
}

// ======== persistent fused kernel ========
// grid 128 x 512thr (8 waves); LDS 156KiB -> 1 block/CU.
// h global layout BLOCKED: chunk s = cg8*64 + row (cg8 = col>>3), 16B per chunk.
// Stage = LINEAR copy (coalesced); MFMA A-read at (cg8*64+row)*16 (conflict-light,
// no swizzle). LSTM: block = (dir, cgp: 2 cgs); wave = (ncg = w>>2, mh = (w>>1)&1,
// kh = w&1). TAGM (bid<32): block = 32 h-cols; wave nc2 = w>>2.
__global__ __launch_bounds__(512)
void tagm_fused(const unsigned short* __restrict__ xt,
                const unsigned short* __restrict__ Wfp,
                const unsigned short* __restrict__ Wbp,
                const unsigned short* __restrict__ Wtp,
                const float* __restrict__ bias_f, const float* __restrict__ bias_b,
                const float* __restrict__ attw, const float* __restrict__ att_fc_b,
                const float* __restrict__ i2h_b, const float* __restrict__ h2h_b,
                const float* __restrict__ fc_w, const float* __restrict__ fc_b,
                unsigned short* __restrict__ h_lstm,  // [2 dir][2 buf] x 128KB blocked
                unsigned short* __restrict__ h_tagm,  // [2 buf] x 128KB blocked
                float* __restrict__ h_f32,            // [64][1024]
                float* __restrict__ att_part,         // [256 slots][512*64] f32 (aliases Wfp/Wbp!)
                unsigned* __restrict__ flags,
                float* __restrict__ out) {
    extern __shared__ char smem[];                    // [0,131072): blocked h image
    char* dumpbase = smem + 131072;                   // 16 KB acc dump (4 slots x 4KB)
    float* auxf = (float*)(smem + 131072 + 16384);    // 8 KB: LSTM c / TAGM h master
    unsigned short* hscr = (unsigned short*)(smem + 131072 + 16384 + 8192);  // 4 KB

    int tid = threadIdx.x;
    int wave = tid >> 6, lane = tid & 63;
    int bid = blockIdx.x;
    int dir = bid & 1, cgp = bid >> 1;                 // cgp 0..63
    int kh = wave & 1, mh = (wave >> 1) & 1, ncg = wave >> 2;
    int q = lane >> 4, c15 = lane & 15;
    int cg = cgp * 2 + ncg;                            // 8-col group 0..127

    // ---- LSTM weight fragments -> registers
    bf16x8 wreg[40];
    {
        const unsigned short* wp = (dir ? Wbp : Wfp) + (size_t)(cg * 2 + kh) * 20480;
#pragma unroll
        for (int f = 0; f < 40; ++f)
            wreg[f] = *(const bf16x8*)(wp + f * 512 + lane * 8);
    }
    int hc = lane & 7;
    int colE = cg * 8 + hc;
    const float* bias = dir ? bias_b : bias_f;
    float b_ii = bias[colE], b_ff = bias[HID + colE];
    float b_gg = bias[2 * HID + colE], b_oo = bias[3 * HID + colE];
    float attw_l = attw[dir * HID + colE];

    for (int i = tid; i < 1024; i += 512) auxf[i] = 0.f;   // c-state [64][16]

    // weights in regs before att_part may clobber Wfp/Wbp
    flag_light(flags, 128, 128, 128 + bid, 1u);

    // =============== LSTM loop ===============
    for (int t = 0; t < SEQ; ++t) {
        int tx = dir ? (SEQ - 1 - t) : t;
        {   // stage h_prev -> LDS: LINEAR blocked copy, fully coalesced
            const char* hsrc = (const char*)h_lstm + (size_t)(dir * 2 + (t & 1)) * 131072;
            char* lbase = smem + (size_t)(tid & 448) * 16;   // wave*1024
#pragma unroll
            for (int i = 0; i < 16; ++i) {
                int s = i * 512 + tid;
                GLOAD_LDS_COHERENT(hsrc + (size_t)s * 16, lbase + (size_t)i * 8192);
            }
        }
        // prefetch x fragments (normal cached loads)
        const unsigned short* xrow = xt + (size_t)tx * BATCH * DIM;
        bf16x8 xa[16];
        if (kh == 0) {
#pragma unroll
            for (int ksl = 0; ksl < 8; ++ksl)
#pragma unroll
                for (int mt = 0; mt < 2; ++mt) {
                    int row = mh * 32 + mt * 16 + c15;
                    xa[ksl * 2 + mt] = *(const bf16x8*)(xrow + row * DIM + ksl * 32 + q * 8);
                }
        }
        __syncthreads();

        f32x4 acc[2][2] = {};
#pragma unroll
        for (int ksl = 0; ksl < 20; ++ksl) {
#pragma unroll
            for (int mt = 0; mt < 2; ++mt) {
                int row = mh * 32 + mt * 16 + c15;
                bf16x8 a;
                if (kh == 0 && ksl < 8) {
                    a = xa[ksl * 2 + mt];
                } else {
                    int kcol = kh * 640 + ksl * 32 + q * 8 - 256;   // h column
                    a = *(const bf16x8*)(smem + (size_t)((kcol >> 3) * 64 + row) * 16);
                }
                acc[mt][0] = __builtin_amdgcn_mfma_f32_16x16x32_bf16(a, wreg[ksl],      acc[mt][0], 0, 0, 0);
                acc[mt][1] = __builtin_amdgcn_mfma_f32_16x16x32_bf16(a, wreg[20 + ksl], acc[mt][1], 0, 0, 0);
            }
        }
        if (kh == 1) {   // dump partials, slot (mh,ncg)
            float* dp = (float*)(dumpbase + (mh * 2 + ncg) * 4096);
#pragma unroll
            for (int mt = 0; mt < 2; ++mt)
#pragma unroll
                for (int nt = 0; nt < 2; ++nt)
                    *(f32x4*)(dp + ((mt * 2 + nt) * 64 + lane) * 4) = acc[mt][nt];
        }
        __syncthreads();
        if (kh == 0) {   // reduce + gates + state update (4 waves in parallel)
            const float* dp = (const float*)(dumpbase + (mh * 2 + ncg) * 4096);
            bool low = (lane & 8) == 0;
#pragma unroll
            for (int mt = 0; mt < 2; ++mt) {
                f32x4 g0 = acc[mt][0] + *(const f32x4*)(dp + ((mt * 2 + 0) * 64 + lane) * 4);
                f32x4 g1 = acc[mt][1] + *(const f32x4*)(dp + ((mt * 2 + 1) * 64 + lane) * 4);
                f32x4 av4;
#pragma unroll
                for (int r = 0; r < 4; ++r) {
                    float fo0 = __shfl(g0[r], lane ^ 8);   // f gate from partner lane
                    float fo1 = __shfl(g1[r], lane ^ 8);   // o gate from partner lane
                    int row = mh * 32 + mt * 16 + q * 4 + r;
                    float si = sigm(g0[r] + b_ii);
                    float sf = sigm(fo0 + b_ff);
                    float tg = tanhf(g1[r] + b_gg);
                    float so = sigm(fo1 + b_oo);
                    float cprev = auxf[row * 16 + ncg * 8 + hc];
                    float cn = sf * cprev + si * tg;
                    float hn = so * tanhf(cn);
                    float av = low ? hn * attw_l : 0.f;
                    av += __shfl_xor(av, 1); av += __shfl_xor(av, 2); av += __shfl_xor(av, 4);
                    av4[r] = av;
                    if (low) {
                        auxf[row * 16 + ncg * 8 + hc] = cn;
                        hscr[ncg * 512 + row * 8 + hc] = f2bf(hn);
                    }
                }
                if (c15 == 0)
                    *(f32x4*)(att_part + (size_t)(bid * 2 + ncg) * 32768 + tx * 64
                              + (mh * 32 + mt * 16 + q * 4)) = av4;
            }
        }
        __syncthreads();   // hscr complete
        if (tid < 128) {   // 2 cgs x 64 rows of 16B chunks -> contiguous 1KB each
            int nn = tid >> 6, row = tid & 63;
            u32x4 v = *(const u32x4*)(hscr + nn * 512 + row * 8);
            size_t chunk = (size_t)((cgp * 2 + nn) * 64 + row);
            store_16B_wt((char*)h_lstm + (size_t)(dir * 2 + ((t + 1) & 1)) * 131072
                         + chunk * 16, v);
        }
        flag_light(flags, dir * 64, 64, dir * 64 + cgp, (unsigned)(t + 1));
    }

    // =============== attention finalize ===============
    flag_barrier(flags, 128, 128, 128 + bid, 2u);   // heavy: att_part cached-written
    {
        int i = tid & 255, half = tid >> 8;
        int item = bid * 256 + i;               // = t*64 + row
        int tt = item >> 6, row = item & 63;
        float s = 0.f;
        const float* p = att_part + (size_t)half * 128 * 32768 + item;
        for (int blk = 0; blk < 128; ++blk)
            s += p[(size_t)blk * 32768];
        float* red = (float*)dumpbase;
        if (half) red[i] = s;
        __syncthreads();
        if (!half)
            out[BATCH * COUT + row * SEQ + tt] = sigm(ATT_SIG_W * (s + red[i] + att_fc_b[0]));
    }
    flag_barrier(flags, 128, 128, 128 + bid, 3u);   // heavy: att out cached-written
    if (bid >= 32) return;

    // =============== TAGM loop (32 blocks x 32 h-cols) ===============
    int nc2 = wave >> 2;
    bf16x8 wt[20];
    {
        const unsigned short* wp = Wtp + (size_t)((bid * 2 + nc2) * 2 + kh) * 10240;
#pragma unroll
        for (int f = 0; f < 20; ++f)
            wt[f] = *(const bf16x8*)(wp + f * 512 + lane * 8);
    }
    int colT = bid * 32 + nc2 * 16 + c15;
    float bbT = i2h_b[colT] + h2h_b[colT];
    for (int i = tid; i < 2048; i += 512) auxf[i] = 0.f;   // h master [64][32]
    __syncthreads();
    const float* attd = out + BATCH * COUT;

    for (int t = 0; t < SEQ; ++t) {
        {   // stage: linear blocked copy
            const char* hsrc = (const char*)h_tagm + (size_t)(t & 1) * 131072;
            char* lbase = smem + (size_t)(tid & 448) * 16;
#pragma unroll
            for (int i = 0; i < 16; ++i) {
                int s = i * 512 + tid;
                GLOAD_LDS_COHERENT(hsrc + (size_t)s * 16, lbase + (size_t)i * 8192);
            }
        }
        const unsigned short* xrow = xt + (size_t)t * BATCH * DIM;
        bf16x8 xa[16];
        if (kh == 0) {
#pragma unroll
            for (int ksl = 0; ksl < 8; ++ksl)
#pragma unroll
                for (int mt = 0; mt < 2; ++mt) {
                    int row = mh * 32 + mt * 16 + c15;
                    xa[ksl * 2 + mt] = *(const bf16x8*)(xrow + row * DIM + ksl * 32 + q * 8);
                }
        }
        __syncthreads();
        f32x4 acc[2] = {};
#pragma unroll
        for (int ksl = 0; ksl < 20; ++ksl) {
#pragma unroll
            for (int mt = 0; mt < 2; ++mt) {
                int row = mh * 32 + mt * 16 + c15;
                bf16x8 a;
                if (kh == 0 && ksl < 8) {
                    a = xa[ksl * 2 + mt];
                } else {
                    int kcol = kh * 640 + ksl * 32 + q * 8 - 256;
                    a = *(const bf16x8*)(smem + (size_t)((kcol >> 3) * 64 + row) * 16);
                }
                acc[mt] = __builtin_amdgcn_mfma_f32_16x16x32_bf16(a, wt[ksl], acc[mt], 0, 0, 0);
            }
        }
        if (kh == 1) {
            float* dp = (float*)(dumpbase + (mh * 2 + nc2) * 2048);
            *(f32x4*)(dp + (0 * 64 + lane) * 4) = acc[0];
            *(f32x4*)(dp + (1 * 64 + lane) * 4) = acc[1];
        }
        __syncthreads();
        if (kh == 0) {
            const float* dp = (const float*)(dumpbase + (mh * 2 + nc2) * 2048);
#pragma unroll
            for (int mt = 0; mt < 2; ++mt) {
                f32x4 g = acc[mt] + *(const f32x4*)(dp + (mt * 64 + lane) * 4);
#pragma unroll
                for (int r = 0; r < 4; ++r) {
                    int row = mh * 32 + mt * 16 + q * 4 + r;
                    float cand = g[r] + bbT;
                    cand = cand > 0.f ? cand : 0.f;
                    float a = attd[row * SEQ + t];
                    float hold = auxf[row * 32 + nc2 * 16 + c15];
                    float hn = a * cand + (1.f - a) * hold;
                    auxf[row * 32 + nc2 * 16 + c15] = hn;
                    hscr[row * 32 + nc2 * 16 + c15] = f2bf(hn);
                }
            }
        }
        __syncthreads();   // hscr complete
        if (tid < 256) {   // 4 cgs x 64 rows -> contiguous 4KB
            int c4 = tid >> 6, row = tid & 63;
            u32x4 v = *(const u32x4*)(hscr + row * 32 + c4 * 8);
            size_t chunk = (size_t)((bid * 4 + c4) * 64 + row);
            store_16B_wt((char*)h_tagm + (size_t)((t + 1) & 1) * 131072 + chunk * 16, v);
        }
        flag_light(flags, 320, 32, 320 + bid, (unsigned)(t + 1));
    }

    // dump final h (f32) for FC
    for (int i = tid; i < 2048; i += 512) {
        int row = i >> 5, cl = i & 31;
        h_f32[row * HID + bid * 32 + cl] = auxf[i];
    }
    flag_barrier(flags, 320, 32, 320 + bid, 600u);   // heavy: h_f32 cached-written

    // =============== FC: 2 batch rows per block ===============
    {
        float* fcp = (float*)dumpbase;   // [2 rows][2 halves][128]
        int c = tid & 127, half = (tid >> 7) & 1, rw = tid >> 8;
        const float* hrow = h_f32 + (size_t)(bid * 2 + rw) * HID;
        float s = 0.f;
        for (int k = half * 512; k < half * 512 + 512; ++k)
            s += hrow[k] * fc_w[(size_t)k * COUT + c];
        fcp[(rw * 2 + half) * 128 + c] = s;
        __syncthreads();
        if (tid < 256) {
            int rr = tid >> 7, cc = tid & 127;
            out[(bid * 2 + rr) * COUT + cc] = fcp[(rr * 2) * 128 + cc]
                                            + fcp[(rr * 2 + 1) * 128 + cc] + fc_b[cc];
        }
    }
}

extern "C" void kernel_launch(void* const* d_in, const int* in_sizes, int n_in,
                              void* d_out, int out_size, void* d_ws, size_t ws_size,
                              hipStream_t stream) {
    const float* x          = (const float*)d_in[0];
    const float* i2h_w      = (const float*)d_in[1];
    const float* i2h_b      = (const float*)d_in[2];
    const float* h2h_w      = (const float*)d_in[3];
    const float* h2h_b      = (const float*)d_in[4];
    const float* fc_w       = (const float*)d_in[5];
    const float* fc_b       = (const float*)d_in[6];
    const float* att_wi_fwd = (const float*)d_in[7];
    const float* att_wh_fwd = (const float*)d_in[8];
    const float* att_b_fwd  = (const float*)d_in[9];
    const float* att_wi_bwd = (const float*)d_in[10];
    const float* att_wh_bwd = (const float*)d_in[11];
    const float* att_b_bwd  = (const float*)d_in[12];
    const float* att_fc_w   = (const float*)d_in[13];
    const float* att_fc_b   = (const float*)d_in[14];
    float* out = (float*)d_out;

    char* ws = (char*)d_ws;
    // setup-phase (dead after packs)
    unsigned short* WfT = (unsigned short*)(ws + 0);          // 10485760
    unsigned short* WbT = (unsigned short*)(ws + 10485760);   // 10485760
    unsigned short* WtT = (unsigned short*)(ws + 20971520);   // 2621440 -> 23592960
    // packed fragment weights
    unsigned short* Wfp = (unsigned short*)(ws + 23592960);   // 10485760
    unsigned short* Wbp = (unsigned short*)(ws + 34078720);   // 10485760 -> 44564480
    unsigned short* Wtp = (unsigned short*)(ws + 17829888);   // 2621440 -> 20451328 (survives)
    // runtime region
    unsigned short* xtb    = (unsigned short*)(ws + 0);        // 16777216
    unsigned short* h_lstm = (unsigned short*)(ws + 16777216); // 524288
    unsigned short* h_tagm = (unsigned short*)(ws + 17301504); // 262144
    float*          h_f32  = (float*)(ws + 17563648);          // 262144
    unsigned*       flags  = (unsigned*)(ws + 17825792);       // 4096 -> 17829888
    // att_part ALIASES Wfp/Wbp (weights register-resident after epoch-1 barrier)
    float*          att_part = (float*)(ws + 23592960);        // 33554432 -> 57147392

    transpose_weights<<<20 * (NGATE / 64), 256, 0, stream>>>(att_wi_fwd, att_wh_fwd, WfT, NGATE);
    transpose_weights<<<20 * (NGATE / 64), 256, 0, stream>>>(att_wi_bwd, att_wh_bwd, WbT, NGATE);
    transpose_weights<<<20 * (HID / 64), 256, 0, stream>>>(i2h_w, h2h_w, WtT, HID);
    pack_lstm<<<256, 256, 0, stream>>>(WfT, Wfp);
    pack_lstm<<<256, 256, 0, stream>>>(WbT, Wbp);
    pack_tagm<<<128, 256, 0, stream>>>(WtT, Wtp);
    transpose_x<<<(SEQ * BATCH * DIM + 255) / 256, 256, 0, stream>>>(x, xtb);
    // zero recurrent state + flags every call
    (void)hipMemsetAsync(ws + 16777216, 0, 17829888 - 16777216, stream);

    static const int SMEM_BYTES = 131072 + 16384 + 8192 + 4096;   // 159744
    (void)hipFuncSetAttribute(reinterpret_cast<const void*>(tagm_fused),
                              hipFuncAttributeMaxDynamicSharedMemorySize, SMEM_BYTES);
    tagm_fused<<<128, 512, SMEM_BYTES, stream>>>(
        xtb, Wfp, Wbp, Wtp, att_b_fwd, att_b_bwd, att_fc_w, att_fc_b,
        i2h_b, h2h_b, fc_w, fc_b, h_lstm, h_tagm, h_f32, att_part, flags, out);
}

// Round 8
// 13092.476 us; speedup vs baseline: 1.1287x; 1.0045x over previous
//
#include <hip/hip_runtime.h>
#include <hip/hip_bf16.h>
#include <cstdint>
#include <cstddef>

constexpr int BATCH = 64;
constexpr int SEQ   = 512;
constexpr int DIM   = 256;
constexpr int HID   = 1024;
constexpr int COUT  = 128;
constexpr int KTOT  = DIM + HID;   // 1280
constexpr int NGATE = 4 * HID;     // 4096
constexpr float ATT_SIG_W = 3.0f;

using bf16x8 = __attribute__((ext_vector_type(8))) __bf16;
using f32x4  = __attribute__((ext_vector_type(4))) float;
using u32x4  = __attribute__((ext_vector_type(4))) unsigned int;

__device__ __forceinline__ unsigned short f2bf(float f) {
    union { float f; unsigned u; } v; v.f = f;
    unsigned u = v.u;
    u += 0x7fffu + ((u >> 16) & 1u);
    return (unsigned short)(u >> 16);
}

__device__ __forceinline__ float sigm(float x) { return 1.f / (1.f + __expf(-x)); }

// 16B write-through store (sc0 sc1); payload must be ext_vector_type (reg quad)
__device__ __forceinline__ void store_16B_wt(void* p, u32x4 v) {
    asm volatile("global_store_dwordx4 %0, %1, off sc0 sc1"
                 :: "v"(p), "v"(v) : "memory");
}

// global->LDS direct copy, 16B/lane, sc0|sc1 (aux=17): bypass L1+L2, read coherent L3
#define GLOAD_LDS_COHERENT(gptr, lptr)                                     \
    __builtin_amdgcn_global_load_lds(                                      \
        (const __attribute__((address_space(1))) void*)(gptr),             \
        (__attribute__((address_space(3))) void*)(lptr), 16, 0, 17)

// ---- weight transpose+convert: out[n][k] = bf16( k<DIM ? wi[k][n] : wh[k-DIM][n] )
__global__ void transpose_weights(const float* __restrict__ wi,
                                  const float* __restrict__ wh,
                                  unsigned short* __restrict__ out, int N) {
    __shared__ float tile[64][65];
    int ntiles = N >> 6;
    int kt = blockIdx.x / ntiles;
    int nt = blockIdx.x % ntiles;
    int k0 = kt << 6, n0 = nt << 6;
    int a = threadIdx.x & 63, g = threadIdx.x >> 6;
#pragma unroll
    for (int p = 0; p < 16; ++p) {
        int kr = p * 4 + g;
        int k = k0 + kr;
        const float* src = (k < DIM) ? (wi + (size_t)k * N) : (wh + (size_t)(k - DIM) * N);
        tile[kr][a] = src[n0 + a];
    }
    __syncthreads();
#pragma unroll
    for (int p = 0; p < 16; ++p) {
        int nr = p * 4 + g;
        out[(size_t)(n0 + nr) * KTOT + (k0 + a)] = f2bf(tile[a][nr]);
    }
}

// ---- x [B][T][D] f32 -> xt [T][B][D] bf16
__global__ void transpose_x(const float* __restrict__ x, unsigned short* __restrict__ xt) {
    size_t idx = (size_t)blockIdx.x * blockDim.x + threadIdx.x;
    if (idx >= (size_t)SEQ * BATCH * DIM) return;
    int d = idx % DIM;
    size_t r = idx / DIM;
    int b = r % BATCH;
    int t = r / BATCH;
    xt[idx] = f2bf(x[((size_t)b * SEQ + t) * DIM + d]);
}

// ---- pack LSTM weights into per-(colgroup, khalf) MFMA fragment order.
__global__ void pack_lstm(const unsigned short* __restrict__ WT,
                          unsigned short* __restrict__ out) {
    int cg = blockIdx.x >> 1, kh = blockIdx.x & 1;
    size_t base = (size_t)blockIdx.x * 20480;
#pragma unroll
    for (int j = 0; j < 80; ++j) {
        int idx = threadIdx.x * 80 + j;
        int frag = idx >> 9;
        int rem = idx & 511;
        int lane = rem >> 3, e = rem & 7;
        int nt = frag / 20, ksl = frag % 20;
        int p = nt * 16 + (lane & 15);
        int origcol = (p >> 3) * 1024 + cg * 8 + (p & 7);
        int k = kh * 640 + ksl * 32 + ((lane >> 4) & 3) * 8 + e;
        out[base + idx] = WT[(size_t)origcol * KTOT + k];
    }
}

// ---- pack TAGM weights: region (cg,kh): 20 frags x 1024B; col = cg*16+(lane&15)
__global__ void pack_tagm(const unsigned short* __restrict__ WT,
                          unsigned short* __restrict__ out) {
    int cg = blockIdx.x >> 1, kh = blockIdx.x & 1;
    size_t base = (size_t)blockIdx.x * 10240;
#pragma unroll
    for (int j = 0; j < 40; ++j) {
        int idx = threadIdx.x * 40 + j;
        int ksl = idx >> 9;
        int rem = idx & 511;
        int lane = rem >> 3, e = rem & 7;
        int origcol = cg * 16 + (lane & 15);
        int k = kh * 640 + ksl * 32 + ((lane >> 4) & 3) * 8 + e;
        out[base + idx] = WT[(size_t)origcol * KTOT + k];
    }
}

// ---- LIGHT per-step barrier: no cache-maintenance fences (h is WT + L2-bypass)
__device__ __forceinline__ void flag_light(unsigned* flags, int base, int cnt,
                                           int myidx, unsigned epoch) {
    asm volatile("s_waitcnt vmcnt(0)" ::: "memory");  // drain own WT stores
    __syncthreads();
    if (threadIdx.x == 0)
        __hip_atomic_store(flags + myidx, epoch, __ATOMIC_RELAXED, __HIP_MEMORY_SCOPE_AGENT);
    if (threadIdx.x < 64) {
        for (;;) {
            bool ok = true;
            for (int j = (int)threadIdx.x; j < cnt; j += 64)
                ok &= (__hip_atomic_load(flags + base + j, __ATOMIC_RELAXED,
                                         __HIP_MEMORY_SCOPE_AGENT) >= epoch);
            if (__all(ok)) break;
            __builtin_amdgcn_s_sleep(1);
        }
    }
    __syncthreads();
}

// ---- HEAVY barrier (phase boundaries only): full release/acquire fences
__device__ __forceinline__ void flag_barrier(unsigned* flags, int base, int cnt,
                                             int myidx, unsigned epoch) {
    __syncthreads();
    if (threadIdx.x == 0) {
        __builtin_amdgcn_fence(__ATOMIC_RELEASE, "agent");   // wbl2
        __hip_atomic_store(flags + myidx, epoch, __ATOMIC_RELAXED, __HIP_MEMORY_SCOPE_AGENT);
    }
    if (threadIdx.x < 64) {
        for (;;) {
            bool ok = true;
            for (int j = (int)threadIdx.x; j < cnt; j += 64)
                ok &= (__hip_atomic_load(flags + base + j, __ATOMIC_RELAXED,
                                         __HIP_MEMORY_SCOPE_AGENT) >= epoch);
            if (__all(ok)) break;
            __builtin_amdgcn_s_sleep(1);
        }
        if (threadIdx.x == 0)
            __builtin_amdgcn_fence(__ATOMIC_ACQUIRE, "agent");   // inv
    }
    __syncthreads();
}

// ======== persistent fused kernel ========
// grid 128 x 512thr (8 waves); LDS 156KiB -> 1 block/CU (2 waves/SIMD).
// __launch_bounds__(512, 2): 2 waves/EU min -> VGPR cap 256 (R7's implicit cap of
// 128 spilled the 160-VGPR weight block to scratch: WRITE_SIZE 245->980MB).
// h global layout BLOCKED: chunk s = cg8*64 + row, 16B/chunk; stage = linear
// coalesced copy; MFMA A-read conflict-light, no swizzle needed.
__global__ __launch_bounds__(512, 2)
void tagm_fused(const unsigned short* __restrict__ xt,
                const unsigned short* __restrict__ Wfp,
                const unsigned short* __restrict__ Wbp,
                const unsigned short* __restrict__ Wtp,
                const float* __restrict__ bias_f, const float* __restrict__ bias_b,
                const float* __restrict__ attw, const float* __restrict__ att_fc_b,
                const float* __restrict__ i2h_b, const float* __restrict__ h2h_b,
                const float* __restrict__ fc_w, const float* __restrict__ fc_b,
                unsigned short* __restrict__ h_lstm,  // [2 dir][2 buf] x 128KB blocked
                unsigned short* __restrict__ h_tagm,  // [2 buf] x 128KB blocked
                float* __restrict__ h_f32,            // [64][1024]
                float* __restrict__ att_part,         // [256 slots][512*64] f32 (aliases Wfp/Wbp!)
                unsigned* __restrict__ flags,
                float* __restrict__ out) {
    extern __shared__ char smem[];                    // [0,131072): blocked h image
    char* dumpbase = smem + 131072;                   // 16 KB acc dump (4 slots x 4KB)
    float* auxf = (float*)(smem + 131072 + 16384);    // 8 KB: LSTM c / TAGM h master
    unsigned short* hscr = (unsigned short*)(smem + 131072 + 16384 + 8192);  // 4 KB

    int tid = threadIdx.x;
    int wave = tid >> 6, lane = tid & 63;
    int bid = blockIdx.x;
    int dir = bid & 1, cgp = bid >> 1;                 // cgp 0..63
    int kh = wave & 1, mh = (wave >> 1) & 1, ncg = wave >> 2;
    int q = lane >> 4, c15 = lane & 15;
    int cg = cgp * 2 + ncg;                            // 8-col group 0..127

    // ---- LSTM weight fragments -> registers
    bf16x8 wreg[40];
    {
        const unsigned short* wp = (dir ? Wbp : Wfp) + (size_t)(cg * 2 + kh) * 20480;
#pragma unroll
        for (int f = 0; f < 40; ++f)
            wreg[f] = *(const bf16x8*)(wp + f * 512 + lane * 8);
    }
    int hc = lane & 7;
    int colE = cg * 8 + hc;
    const float* bias = dir ? bias_b : bias_f;
    float b_ii = bias[colE], b_ff = bias[HID + colE];
    float b_gg = bias[2 * HID + colE], b_oo = bias[3 * HID + colE];
    float attw_l = attw[dir * HID + colE];

    for (int i = tid; i < 1024; i += 512) auxf[i] = 0.f;   // c-state [64][16]

    // weights in regs before att_part may clobber Wfp/Wbp
    flag_light(flags, 128, 128, 128 + bid, 1u);

    // =============== LSTM loop ===============
    for (int t = 0; t < SEQ; ++t) {
        int tx = dir ? (SEQ - 1 - t) : t;
        {   // stage h_prev -> LDS: LINEAR blocked copy, fully coalesced
            const char* hsrc = (const char*)h_lstm + (size_t)(dir * 2 + (t & 1)) * 131072;
            char* lbase = smem + (size_t)(tid & 448) * 16;   // wave*1024
#pragma unroll
            for (int i = 0; i < 16; ++i) {
                int s = i * 512 + tid;
                GLOAD_LDS_COHERENT(hsrc + (size_t)s * 16, lbase + (size_t)i * 8192);
            }
        }
        // prefetch x fragments (normal cached loads)
        const unsigned short* xrow = xt + (size_t)tx * BATCH * DIM;
        bf16x8 xa[16];
        if (kh == 0) {
#pragma unroll
            for (int ksl = 0; ksl < 8; ++ksl)
#pragma unroll
                for (int mt = 0; mt < 2; ++mt) {
                    int row = mh * 32 + mt * 16 + c15;
                    xa[ksl * 2 + mt] = *(const bf16x8*)(xrow + row * DIM + ksl * 32 + q * 8);
                }
        }
        __syncthreads();

        f32x4 acc[2][2] = {};
#pragma unroll
        for (int ksl = 0; ksl < 20; ++ksl) {
#pragma unroll
            for (int mt = 0; mt < 2; ++mt) {
                int row = mh * 32 + mt * 16 + c15;
                bf16x8 a;
                if (kh == 0 && ksl < 8) {
                    a = xa[ksl * 2 + mt];
                } else {
                    int kcol = kh * 640 + ksl * 32 + q * 8 - 256;   // h column
                    a = *(const bf16x8*)(smem + (size_t)((kcol >> 3) * 64 + row) * 16);
                }
                acc[mt][0] = __builtin_amdgcn_mfma_f32_16x16x32_bf16(a, wreg[ksl],      acc[mt][0], 0, 0, 0);
                acc[mt][1] = __builtin_amdgcn_mfma_f32_16x16x32_bf16(a, wreg[20 + ksl], acc[mt][1], 0, 0, 0);
            }
        }
        if (kh == 1) {   // dump partials, slot (mh,ncg)
            float* dp = (float*)(dumpbase + (mh * 2 + ncg) * 4096);
#pragma unroll
            for (int mt = 0; mt < 2; ++mt)
#pragma unroll
                for (int nt = 0; nt < 2; ++nt)
                    *(f32x4*)(dp + ((mt * 2 + nt) * 64 + lane) * 4) = acc[mt][nt];
        }
        __syncthreads();
        if (kh == 0) {   // reduce + gates + state update (4 waves in parallel)
            const float* dp = (const float*)(dumpbase + (mh * 2 + ncg) * 4096);
            bool low = (lane & 8) == 0;
#pragma unroll
            for (int mt = 0; mt < 2; ++mt) {
                f32x4 g0 = acc[mt][0] + *(const f32x4*)(dp + ((mt * 2 + 0) * 64 + lane) * 4);
                f32x4 g1 = acc[mt][1] + *(const f32x4*)(dp + ((mt * 2 + 1) * 64 + lane) * 4);
                f32x4 av4;
#pragma unroll
                for (int r = 0; r < 4; ++r) {
                    float fo0 = __shfl(g0[r], lane ^ 8);   // f gate from partner lane
                    float fo1 = __shfl(g1[r], lane ^ 8);   // o gate from partner lane
                    int row = mh * 32 + mt * 16 + q * 4 + r;
                    float si = sigm(g0[r] + b_ii);
                    float sf = sigm(fo0 + b_ff);
                    float tg = tanhf(g1[r] + b_gg);
                    float so = sigm(fo1 + b_oo);
                    float cprev = auxf[row * 16 + ncg * 8 + hc];
                    float cn = sf * cprev + si * tg;
                    float hn = so * tanhf(cn);
                    float av = low ? hn * attw_l : 0.f;
                    av += __shfl_xor(av, 1); av += __shfl_xor(av, 2); av += __shfl_xor(av, 4);
                    av4[r] = av;
                    if (low) {
                        auxf[row * 16 + ncg * 8 + hc] = cn;
                        hscr[ncg * 512 + row * 8 + hc] = f2bf(hn);
                    }
                }
                if (c15 == 0)
                    *(f32x4*)(att_part + (size_t)(bid * 2 + ncg) * 32768 + tx * 64
                              + (mh * 32 + mt * 16 + q * 4)) = av4;
            }
        }
        __syncthreads();   // hscr complete
        if (tid < 128) {   // 2 cgs x 64 rows of 16B chunks -> contiguous 1KB each
            int nn = tid >> 6, row = tid & 63;
            u32x4 v = *(const u32x4*)(hscr + nn * 512 + row * 8);
            size_t chunk = (size_t)((cgp * 2 + nn) * 64 + row);
            store_16B_wt((char*)h_lstm + (size_t)(dir * 2 + ((t + 1) & 1)) * 131072
                         + chunk * 16, v);
        }
        flag_light(flags, dir * 64, 64, dir * 64 + cgp, (unsigned)(t + 1));
    }

    // =============== attention finalize ===============
    flag_barrier(flags, 128, 128, 128 + bid, 2u);   // heavy: att_part cached-written
    {
        int i = tid & 255, half = tid >> 8;
        int item = bid * 256 + i;               // = t*64 + row
        int tt = item >> 6, row = item & 63;
        float s = 0.f;
        const float* p = att_part + (size_t)half * 128 * 32768 + item;
        for (int blk = 0; blk < 128; ++blk)
            s += p[(size_t)blk * 32768];
        float* red = (float*)dumpbase;
        if (half) red[i] = s;
        __syncthreads();
        if (!half)
            out[BATCH * COUT + row * SEQ + tt] = sigm(ATT_SIG_W * (s + red[i] + att_fc_b[0]));
    }
    flag_barrier(flags, 128, 128, 128 + bid, 3u);   // heavy: att out cached-written
    if (bid >= 32) return;

    // =============== TAGM loop (32 blocks x 32 h-cols) ===============
    int nc2 = wave >> 2;
    bf16x8 wt[20];
    {
        const unsigned short* wp = Wtp + (size_t)((bid * 2 + nc2) * 2 + kh) * 10240;
#pragma unroll
        for (int f = 0; f < 20; ++f)
            wt[f] = *(const bf16x8*)(wp + f * 512 + lane * 8);
    }
    int colT = bid * 32 + nc2 * 16 + c15;
    float bbT = i2h_b[colT] + h2h_b[colT];
    for (int i = tid; i < 2048; i += 512) auxf[i] = 0.f;   // h master [64][32]
    __syncthreads();
    const float* attd = out + BATCH * COUT;

    for (int t = 0; t < SEQ; ++t) {
        {   // stage: linear blocked copy
            const char* hsrc = (const char*)h_tagm + (size_t)(t & 1) * 131072;
            char* lbase = smem + (size_t)(tid & 448) * 16;
#pragma unroll
            for (int i = 0; i < 16; ++i) {
                int s = i * 512 + tid;
                GLOAD_LDS_COHERENT(hsrc + (size_t)s * 16, lbase + (size_t)i * 8192);
            }
        }
        const unsigned short* xrow = xt + (size_t)t * BATCH * DIM;
        bf16x8 xa[16];
        if (kh == 0) {
#pragma unroll
            for (int ksl = 0; ksl < 8; ++ksl)
#pragma unroll
                for (int mt = 0; mt < 2; ++mt) {
                    int row = mh * 32 + mt * 16 + c15;
                    xa[ksl * 2 + mt] = *(const bf16x8*)(xrow + row * DIM + ksl * 32 + q * 8);
                }
        }
        __syncthreads();
        f32x4 acc[2] = {};
#pragma unroll
        for (int ksl = 0; ksl < 20; ++ksl) {
#pragma unroll
            for (int mt = 0; mt < 2; ++mt) {
                int row = mh * 32 + mt * 16 + c15;
                bf16x8 a;
                if (kh == 0 && ksl < 8) {
                    a = xa[ksl * 2 + mt];
                } else {
                    int kcol = kh * 640 + ksl * 32 + q * 8 - 256;
                    a = *(const bf16x8*)(smem + (size_t)((kcol >> 3) * 64 + row) * 16);
                }
                acc[mt] = __builtin_amdgcn_mfma_f32_16x16x32_bf16(a, wt[ksl], acc[mt], 0, 0, 0);
            }
        }
        if (kh == 1) {
            float* dp = (float*)(dumpbase + (mh * 2 + nc2) * 2048);
            *(f32x4*)(dp + (0 * 64 + lane) * 4) = acc[0];
            *(f32x4*)(dp + (1 * 64 + lane) * 4) = acc[1];
        }
        __syncthreads();
        if (kh == 0) {
            const float* dp = (const float*)(dumpbase + (mh * 2 + nc2) * 2048);
#pragma unroll
            for (int mt = 0; mt < 2; ++mt) {
                f32x4 g = acc[mt] + *(const f32x4*)(dp + (mt * 64 + lane) * 4);
#pragma unroll
                for (int r = 0; r < 4; ++r) {
                    int row = mh * 32 + mt * 16 + q * 4 + r;
                    float cand = g[r] + bbT;
                    cand = cand > 0.f ? cand : 0.f;
                    float a = attd[row * SEQ + t];
                    float hold = auxf[row * 32 + nc2 * 16 + c15];
                    float hn = a * cand + (1.f - a) * hold;
                    auxf[row * 32 + nc2 * 16 + c15] = hn;
                    hscr[row * 32 + nc2 * 16 + c15] = f2bf(hn);
                }
            }
        }
        __syncthreads();   // hscr complete
        if (tid < 256) {   // 4 cgs x 64 rows -> contiguous 4KB
            int c4 = tid >> 6, row = tid & 63;
            u32x4 v = *(const u32x4*)(hscr + row * 32 + c4 * 8);
            size_t chunk = (size_t)((bid * 4 + c4) * 64 + row);
            store_16B_wt((char*)h_tagm + (size_t)((t + 1) & 1) * 131072 + chunk * 16, v);
        }
        flag_light(flags, 320, 32, 320 + bid, (unsigned)(t + 1));
    }

    // dump final h (f32) for FC
    for (int i = tid; i < 2048; i += 512) {
        int row = i >> 5, cl = i & 31;
        h_f32[row * HID + bid * 32 + cl] = auxf[i];
    }
    flag_barrier(flags, 320, 32, 320 + bid, 600u);   // heavy: h_f32 cached-written

    // =============== FC: 2 batch rows per block ===============
    {
        float* fcp = (float*)dumpbase;   // [2 rows][2 halves][128]
        int c = tid & 127, half = (tid >> 7) & 1, rw = tid >> 8;
        const float* hrow = h_f32 + (size_t)(bid * 2 + rw) * HID;
        float s = 0.f;
        for (int k = half * 512; k < half * 512 + 512; ++k)
            s += hrow[k] * fc_w[(size_t)k * COUT + c];
        fcp[(rw * 2 + half) * 128 + c] = s;
        __syncthreads();
        if (tid < 256) {
            int rr = tid >> 7, cc = tid & 127;
            out[(bid * 2 + rr) * COUT + cc] = fcp[(rr * 2) * 128 + cc]
                                            + fcp[(rr * 2 + 1) * 128 + cc] + fc_b[cc];
        }
    }
}

extern "C" void kernel_launch(void* const* d_in, const int* in_sizes, int n_in,
                              void* d_out, int out_size, void* d_ws, size_t ws_size,
                              hipStream_t stream) {
    const float* x          = (const float*)d_in[0];
    const float* i2h_w      = (const float*)d_in[1];
    const float* i2h_b      = (const float*)d_in[2];
    const float* h2h_w      = (const float*)d_in[3];
    const float* h2h_b      = (const float*)d_in[4];
    const float* fc_w       = (const float*)d_in[5];
    const float* fc_b       = (const float*)d_in[6];
    const float* att_wi_fwd = (const float*)d_in[7];
    const float* att_wh_fwd = (const float*)d_in[8];
    const float* att_b_fwd  = (const float*)d_in[9];
    const float* att_wi_bwd = (const float*)d_in[10];
    const float* att_wh_bwd = (const float*)d_in[11];
    const float* att_b_bwd  = (const float*)d_in[12];
    const float* att_fc_w   = (const float*)d_in[13];
    const float* att_fc_b   = (const float*)d_in[14];
    float* out = (float*)d_out;

    char* ws = (char*)d_ws;
    // setup-phase (dead after packs)
    unsigned short* WfT = (unsigned short*)(ws + 0);          // 10485760
    unsigned short* WbT = (unsigned short*)(ws + 10485760);   // 10485760
    unsigned short* WtT = (unsigned short*)(ws + 20971520);   // 2621440 -> 23592960
    // packed fragment weights
    unsigned short* Wfp = (unsigned short*)(ws + 23592960);   // 10485760
    unsigned short* Wbp = (unsigned short*)(ws + 34078720);   // 10485760 -> 44564480
    unsigned short* Wtp = (unsigned short*)(ws + 17829888);   // 2621440 -> 20451328 (survives)
    // runtime region
    unsigned short* xtb    = (unsigned short*)(ws + 0);        // 16777216
    unsigned short* h_lstm = (unsigned short*)(ws + 16777216); // 524288
    unsigned short* h_tagm = (unsigned short*)(ws + 17301504); // 262144
    float*          h_f32  = (float*)(ws + 17563648);          // 262144
    unsigned*       flags  = (unsigned*)(ws + 17825792);       // 4096 -> 17829888
    // att_part ALIASES Wfp/Wbp (weights register-resident after epoch-1 barrier)
    float*          att_part = (float*)(ws + 23592960);        // 33554432 -> 57147392

    transpose_weights<<<20 * (NGATE / 64), 256, 0, stream>>>(att_wi_fwd, att_wh_fwd, WfT, NGATE);
    transpose_weights<<<20 * (NGATE / 64), 256, 0, stream>>>(att_wi_bwd, att_wh_bwd, WbT, NGATE);
    transpose_weights<<<20 * (HID / 64), 256, 0, stream>>>(i2h_w, h2h_w, WtT, HID);
    pack_lstm<<<256, 256, 0, stream>>>(WfT, Wfp);
    pack_lstm<<<256, 256, 0, stream>>>(WbT, Wbp);
    pack_tagm<<<128, 256, 0, stream>>>(WtT, Wtp);
    transpose_x<<<(SEQ * BATCH * DIM + 255) / 256, 256, 0, stream>>>(x, xtb);
    // zero recurrent state + flags every call
    (void)hipMemsetAsync(ws + 16777216, 0, 17829888 - 16777216, stream);

    static const int SMEM_BYTES = 131072 + 16384 + 8192 + 4096;   // 159744
    (void)hipFuncSetAttribute(reinterpret_cast<const void*>(tagm_fused),
                              hipFuncAttributeMaxDynamicSharedMemorySize, SMEM_BYTES);
    tagm_fused<<<128, 512, SMEM_BYTES, stream>>>(
        xtb, Wfp, Wbp, Wtp, att_b_fwd, att_b_bwd, att_fc_w, att_fc_b,
        i2h_b, h2h_b, fc_w, fc_b, h_lstm, h_tagm, h_f32, att_part, flags, out);
}

// Round 9
// 13085.143 us; speedup vs baseline: 1.1293x; 1.0006x over previous
//
#include <hip/hip_runtime.h>
#include <hip/hip_bf16.h>
#include <cstdint>
#include <cstddef>

constexpr int BATCH = 64;
constexpr int SEQ   = 512;
constexpr int DIM   = 256;
constexpr int HID   = 1024;
constexpr int COUT  = 128;
constexpr int KTOT  = DIM + HID;   // 1280
constexpr int NGATE = 4 * HID;     // 4096
constexpr float ATT_SIG_W = 3.0f;

using bf16x8 = __attribute__((ext_vector_type(8))) __bf16;
using f32x4  = __attribute__((ext_vector_type(4))) float;
using u32x4  = __attribute__((ext_vector_type(4))) unsigned int;

__device__ __forceinline__ unsigned short f2bf(float f) {
    union { float f; unsigned u; } v; v.f = f;
    unsigned u = v.u;
    u += 0x7fffu + ((u >> 16) & 1u);
    return (unsigned short)(u >> 16);
}

__device__ __forceinline__ float sigm(float x) { return 1.f / (1.f + __expf(-x)); }

// 16B write-through store (sc0 sc1); payload must be ext_vector_type (reg quad)
__device__ __forceinline__ void store_16B_wt(void* p, u32x4 v) {
    asm volatile("global_store_dwordx4 %0, %1, off sc0 sc1"
                 :: "v"(p), "v"(v) : "memory");
}

// global->LDS direct copy, 16B/lane, sc0|sc1 (aux=17): bypass L1+L2, read coherent L3
#define GLOAD_LDS_COHERENT(gptr, lptr)                                     \
    __builtin_amdgcn_global_load_lds(                                      \
        (const __attribute__((address_space(1))) void*)(gptr),             \
        (__attribute__((address_space(3))) void*)(lptr), 16, 0, 17)

// ---- weight transpose+convert: out[n][k] = bf16( k<DIM ? wi[k][n] : wh[k-DIM][n] )
__global__ void transpose_weights(const float* __restrict__ wi,
                                  const float* __restrict__ wh,
                                  unsigned short* __restrict__ out, int N) {
    __shared__ float tile[64][65];
    int ntiles = N >> 6;
    int kt = blockIdx.x / ntiles;
    int nt = blockIdx.x % ntiles;
    int k0 = kt << 6, n0 = nt << 6;
    int a = threadIdx.x & 63, g = threadIdx.x >> 6;
#pragma unroll
    for (int p = 0; p < 16; ++p) {
        int kr = p * 4 + g;
        int k = k0 + kr;
        const float* src = (k < DIM) ? (wi + (size_t)k * N) : (wh + (size_t)(k - DIM) * N);
        tile[kr][a] = src[n0 + a];
    }
    __syncthreads();
#pragma unroll
    for (int p = 0; p < 16; ++p) {
        int nr = p * 4 + g;
        out[(size_t)(n0 + nr) * KTOT + (k0 + a)] = f2bf(tile[a][nr]);
    }
}

// ---- x [B][T][D] f32 -> xt [T][B][D] bf16
__global__ void transpose_x(const float* __restrict__ x, unsigned short* __restrict__ xt) {
    size_t idx = (size_t)blockIdx.x * blockDim.x + threadIdx.x;
    if (idx >= (size_t)SEQ * BATCH * DIM) return;
    int d = idx % DIM;
    size_t r = idx / DIM;
    int b = r % BATCH;
    int t = r / BATCH;
    xt[idx] = f2bf(x[((size_t)b * SEQ + t) * DIM + d]);
}

// ---- pack LSTM weights into per-(colgroup, khalf) MFMA fragment order.
__global__ void pack_lstm(const unsigned short* __restrict__ WT,
                          unsigned short* __restrict__ out) {
    int cg = blockIdx.x >> 1, kh = blockIdx.x & 1;
    size_t base = (size_t)blockIdx.x * 20480;
#pragma unroll
    for (int j = 0; j < 80; ++j) {
        int idx = threadIdx.x * 80 + j;
        int frag = idx >> 9;
        int rem = idx & 511;
        int lane = rem >> 3, e = rem & 7;
        int nt = frag / 20, ksl = frag % 20;
        int p = nt * 16 + (lane & 15);
        int origcol = (p >> 3) * 1024 + cg * 8 + (p & 7);
        int k = kh * 640 + ksl * 32 + ((lane >> 4) & 3) * 8 + e;
        out[base + idx] = WT[(size_t)origcol * KTOT + k];
    }
}

// ---- pack TAGM weights: region (cg,kh): 20 frags x 1024B; col = cg*16+(lane&15)
__global__ void pack_tagm(const unsigned short* __restrict__ WT,
                          unsigned short* __restrict__ out) {
    int cg = blockIdx.x >> 1, kh = blockIdx.x & 1;
    size_t base = (size_t)blockIdx.x * 10240;
#pragma unroll
    for (int j = 0; j < 40; ++j) {
        int idx = threadIdx.x * 40 + j;
        int ksl = idx >> 9;
        int rem = idx & 511;
        int lane = rem >> 3, e = rem & 7;
        int origcol = cg * 16 + (lane & 15);
        int k = kh * 640 + ksl * 32 + ((lane >> 4) & 3) * 8 + e;
        out[base + idx] = WT[(size_t)origcol * KTOT + k];
    }
}

// ---- LIGHT per-step barrier: no cache-maintenance fences (h is WT + L2-bypass)
__device__ __forceinline__ void flag_light(unsigned* flags, int base, int cnt,
                                           int myidx, unsigned epoch) {
    asm volatile("s_waitcnt vmcnt(0)" ::: "memory");  // drain own WT stores
    __syncthreads();
    if (threadIdx.x == 0)
        __hip_atomic_store(flags + myidx, epoch, __ATOMIC_RELAXED, __HIP_MEMORY_SCOPE_AGENT);
    if (threadIdx.x < 64) {
        for (;;) {
            bool ok = true;
            for (int j = (int)threadIdx.x; j < cnt; j += 64)
                ok &= (__hip_atomic_load(flags + base + j, __ATOMIC_RELAXED,
                                         __HIP_MEMORY_SCOPE_AGENT) >= epoch);
            if (__all(ok)) break;
            __builtin_amdgcn_s_sleep(1);
        }
    }
    __syncthreads();
}

// ---- HEAVY barrier (phase boundaries only): full release/acquire fences
__device__ __forceinline__ void flag_barrier(unsigned* flags, int base, int cnt,
                                             int myidx, unsigned epoch) {
    __syncthreads();
    if (threadIdx.x == 0) {
        __builtin_amdgcn_fence(__ATOMIC_RELEASE, "agent");   // wbl2
        __hip_atomic_store(flags + myidx, epoch, __ATOMIC_RELAXED, __HIP_MEMORY_SCOPE_AGENT);
    }
    if (threadIdx.x < 64) {
        for (;;) {
            bool ok = true;
            for (int j = (int)threadIdx.x; j < cnt; j += 64)
                ok &= (__hip_atomic_load(flags + base + j, __ATOMIC_RELAXED,
                                         __HIP_MEMORY_SCOPE_AGENT) >= epoch);
            if (__all(ok)) break;
            __builtin_amdgcn_s_sleep(1);
        }
        if (threadIdx.x == 0)
            __builtin_amdgcn_fence(__ATOMIC_ACQUIRE, "agent");   // inv
    }
    __syncthreads();
}

// ======== persistent fused kernel ========
// grid 128 x 512thr (8 waves); LDS 156KiB -> 1 block/CU (2 waves/SIMD).
// amdgpu_waves_per_eu(2,2): PIN allocator to 2 waves/EU -> 256 VGPR budget.
// (launch_bounds 2nd arg only sets the range MINIMUM; with dynamic LDS unknown
// at compile time the allocator targeted 4 waves/EU = 128 VGPR and spilled the
// 160-VGPR weight block to scratch: R7/R8 WRITE_SIZE 980MB, VGPR_Count 128.)
__global__ __launch_bounds__(512)
__attribute__((amdgpu_waves_per_eu(2, 2)))
void tagm_fused(const unsigned short* __restrict__ xt,
                const unsigned short* __restrict__ Wfp,
                const unsigned short* __restrict__ Wbp,
                const unsigned short* __restrict__ Wtp,
                const float* __restrict__ bias_f, const float* __restrict__ bias_b,
                const float* __restrict__ attw, const float* __restrict__ att_fc_b,
                const float* __restrict__ i2h_b, const float* __restrict__ h2h_b,
                const float* __restrict__ fc_w, const float* __restrict__ fc_b,
                unsigned short* __restrict__ h_lstm,  // [2 dir][2 buf] x 128KB blocked
                unsigned short* __restrict__ h_tagm,  // [2 buf] x 128KB blocked
                float* __restrict__ h_f32,            // [64][1024]
                float* __restrict__ att_part,         // [256 slots][512*64] f32 (aliases Wfp/Wbp!)
                unsigned* __restrict__ flags,
                float* __restrict__ out) {
    extern __shared__ char smem[];                    // [0,131072): blocked h image
    char* dumpbase = smem + 131072;                   // 16 KB acc dump (4 slots x 4KB)
    float* auxf = (float*)(smem + 131072 + 16384);    // 8 KB: LSTM c / TAGM h master
    unsigned short* hscr = (unsigned short*)(smem + 131072 + 16384 + 8192);  // 4 KB

    int tid = threadIdx.x;
    int wave = tid >> 6, lane = tid & 63;
    int bid = blockIdx.x;
    int dir = bid & 1, cgp = bid >> 1;                 // cgp 0..63
    int kh = wave & 1, mh = (wave >> 1) & 1, ncg = wave >> 2;
    int q = lane >> 4, c15 = lane & 15;
    int cg = cgp * 2 + ncg;                            // 8-col group 0..127

    // ---- LSTM weight fragments -> registers
    bf16x8 wreg[40];
    {
        const unsigned short* wp = (dir ? Wbp : Wfp) + (size_t)(cg * 2 + kh) * 20480;
#pragma unroll
        for (int f = 0; f < 40; ++f)
            wreg[f] = *(const bf16x8*)(wp + f * 512 + lane * 8);
    }
    int hc = lane & 7;
    int colE = cg * 8 + hc;
    const float* bias = dir ? bias_b : bias_f;
    float b_ii = bias[colE], b_ff = bias[HID + colE];
    float b_gg = bias[2 * HID + colE], b_oo = bias[3 * HID + colE];
    float attw_l = attw[dir * HID + colE];

    for (int i = tid; i < 1024; i += 512) auxf[i] = 0.f;   // c-state [64][16]

    // weights in regs before att_part may clobber Wfp/Wbp
    flag_light(flags, 128, 128, 128 + bid, 1u);

    // =============== LSTM loop ===============
    for (int t = 0; t < SEQ; ++t) {
        int tx = dir ? (SEQ - 1 - t) : t;
        {   // stage h_prev -> LDS: LINEAR blocked copy, fully coalesced
            const char* hsrc = (const char*)h_lstm + (size_t)(dir * 2 + (t & 1)) * 131072;
            char* lbase = smem + (size_t)(tid & 448) * 16;   // wave*1024
#pragma unroll
            for (int i = 0; i < 16; ++i) {
                int s = i * 512 + tid;
                GLOAD_LDS_COHERENT(hsrc + (size_t)s * 16, lbase + (size_t)i * 8192);
            }
        }
        // prefetch x fragments (normal cached loads)
        const unsigned short* xrow = xt + (size_t)tx * BATCH * DIM;
        bf16x8 xa[16];
        if (kh == 0) {
#pragma unroll
            for (int ksl = 0; ksl < 8; ++ksl)
#pragma unroll
                for (int mt = 0; mt < 2; ++mt) {
                    int row = mh * 32 + mt * 16 + c15;
                    xa[ksl * 2 + mt] = *(const bf16x8*)(xrow + row * DIM + ksl * 32 + q * 8);
                }
        }
        __syncthreads();

        f32x4 acc[2][2] = {};
#pragma unroll
        for (int ksl = 0; ksl < 20; ++ksl) {
#pragma unroll
            for (int mt = 0; mt < 2; ++mt) {
                int row = mh * 32 + mt * 16 + c15;
                bf16x8 a;
                if (kh == 0 && ksl < 8) {
                    a = xa[ksl * 2 + mt];
                } else {
                    int kcol = kh * 640 + ksl * 32 + q * 8 - 256;   // h column
                    a = *(const bf16x8*)(smem + (size_t)((kcol >> 3) * 64 + row) * 16);
                }
                acc[mt][0] = __builtin_amdgcn_mfma_f32_16x16x32_bf16(a, wreg[ksl],      acc[mt][0], 0, 0, 0);
                acc[mt][1] = __builtin_amdgcn_mfma_f32_16x16x32_bf16(a, wreg[20 + ksl], acc[mt][1], 0, 0, 0);
            }
        }
        if (kh == 1) {   // dump partials, slot (mh,ncg)
            float* dp = (float*)(dumpbase + (mh * 2 + ncg) * 4096);
#pragma unroll
            for (int mt = 0; mt < 2; ++mt)
#pragma unroll
                for (int nt = 0; nt < 2; ++nt)
                    *(f32x4*)(dp + ((mt * 2 + nt) * 64 + lane) * 4) = acc[mt][nt];
        }
        __syncthreads();
        if (kh == 0) {   // reduce + gates + state update (4 waves in parallel)
            const float* dp = (const float*)(dumpbase + (mh * 2 + ncg) * 4096);
            bool low = (lane & 8) == 0;
#pragma unroll
            for (int mt = 0; mt < 2; ++mt) {
                f32x4 g0 = acc[mt][0] + *(const f32x4*)(dp + ((mt * 2 + 0) * 64 + lane) * 4);
                f32x4 g1 = acc[mt][1] + *(const f32x4*)(dp + ((mt * 2 + 1) * 64 + lane) * 4);
                f32x4 av4;
#pragma unroll
                for (int r = 0; r < 4; ++r) {
                    float fo0 = __shfl(g0[r], lane ^ 8);   // f gate from partner lane
                    float fo1 = __shfl(g1[r], lane ^ 8);   // o gate from partner lane
                    int row = mh * 32 + mt * 16 + q * 4 + r;
                    float si = sigm(g0[r] + b_ii);
                    float sf = sigm(fo0 + b_ff);
                    float tg = tanhf(g1[r] + b_gg);
                    float so = sigm(fo1 + b_oo);
                    float cprev = auxf[row * 16 + ncg * 8 + hc];
                    float cn = sf * cprev + si * tg;
                    float hn = so * tanhf(cn);
                    float av = low ? hn * attw_l : 0.f;
                    av += __shfl_xor(av, 1); av += __shfl_xor(av, 2); av += __shfl_xor(av, 4);
                    av4[r] = av;
                    if (low) {
                        auxf[row * 16 + ncg * 8 + hc] = cn;
                        hscr[ncg * 512 + row * 8 + hc] = f2bf(hn);
                    }
                }
                if (c15 == 0)
                    *(f32x4*)(att_part + (size_t)(bid * 2 + ncg) * 32768 + tx * 64
                              + (mh * 32 + mt * 16 + q * 4)) = av4;
            }
        }
        __syncthreads();   // hscr complete
        if (tid < 128) {   // 2 cgs x 64 rows of 16B chunks -> contiguous 1KB each
            int nn = tid >> 6, row = tid & 63;
            u32x4 v = *(const u32x4*)(hscr + nn * 512 + row * 8);
            size_t chunk = (size_t)((cgp * 2 + nn) * 64 + row);
            store_16B_wt((char*)h_lstm + (size_t)(dir * 2 + ((t + 1) & 1)) * 131072
                         + chunk * 16, v);
        }
        flag_light(flags, dir * 64, 64, dir * 64 + cgp, (unsigned)(t + 1));
    }

    // =============== attention finalize ===============
    flag_barrier(flags, 128, 128, 128 + bid, 2u);   // heavy: att_part cached-written
    {
        int i = tid & 255, half = tid >> 8;
        int item = bid * 256 + i;               // = t*64 + row
        int tt = item >> 6, row = item & 63;
        float s = 0.f;
        const float* p = att_part + (size_t)half * 128 * 32768 + item;
        for (int blk = 0; blk < 128; ++blk)
            s += p[(size_t)blk * 32768];
        float* red = (float*)dumpbase;
        if (half) red[i] = s;
        __syncthreads();
        if (!half)
            out[BATCH * COUT + row * SEQ + tt] = sigm(ATT_SIG_W * (s + red[i] + att_fc_b[0]));
    }
    flag_barrier(flags, 128, 128, 128 + bid, 3u);   // heavy: att out cached-written
    if (bid >= 32) return;

    // =============== TAGM loop (32 blocks x 32 h-cols) ===============
    int nc2 = wave >> 2;
    bf16x8 wt[20];
    {
        const unsigned short* wp = Wtp + (size_t)((bid * 2 + nc2) * 2 + kh) * 10240;
#pragma unroll
        for (int f = 0; f < 20; ++f)
            wt[f] = *(const bf16x8*)(wp + f * 512 + lane * 8);
    }
    int colT = bid * 32 + nc2 * 16 + c15;
    float bbT = i2h_b[colT] + h2h_b[colT];
    for (int i = tid; i < 2048; i += 512) auxf[i] = 0.f;   // h master [64][32]
    __syncthreads();
    const float* attd = out + BATCH * COUT;

    for (int t = 0; t < SEQ; ++t) {
        {   // stage: linear blocked copy
            const char* hsrc = (const char*)h_tagm + (size_t)(t & 1) * 131072;
            char* lbase = smem + (size_t)(tid & 448) * 16;
#pragma unroll
            for (int i = 0; i < 16; ++i) {
                int s = i * 512 + tid;
                GLOAD_LDS_COHERENT(hsrc + (size_t)s * 16, lbase + (size_t)i * 8192);
            }
        }
        const unsigned short* xrow = xt + (size_t)t * BATCH * DIM;
        bf16x8 xa[16];
        if (kh == 0) {
#pragma unroll
            for (int ksl = 0; ksl < 8; ++ksl)
#pragma unroll
                for (int mt = 0; mt < 2; ++mt) {
                    int row = mh * 32 + mt * 16 + c15;
                    xa[ksl * 2 + mt] = *(const bf16x8*)(xrow + row * DIM + ksl * 32 + q * 8);
                }
        }
        __syncthreads();
        f32x4 acc[2] = {};
#pragma unroll
        for (int ksl = 0; ksl < 20; ++ksl) {
#pragma unroll
            for (int mt = 0; mt < 2; ++mt) {
                int row = mh * 32 + mt * 16 + c15;
                bf16x8 a;
                if (kh == 0 && ksl < 8) {
                    a = xa[ksl * 2 + mt];
                } else {
                    int kcol = kh * 640 + ksl * 32 + q * 8 - 256;
                    a = *(const bf16x8*)(smem + (size_t)((kcol >> 3) * 64 + row) * 16);
                }
                acc[mt] = __builtin_amdgcn_mfma_f32_16x16x32_bf16(a, wt[ksl], acc[mt], 0, 0, 0);
            }
        }
        if (kh == 1) {
            float* dp = (float*)(dumpbase + (mh * 2 + nc2) * 2048);
            *(f32x4*)(dp + (0 * 64 + lane) * 4) = acc[0];
            *(f32x4*)(dp + (1 * 64 + lane) * 4) = acc[1];
        }
        __syncthreads();
        if (kh == 0) {
            const float* dp = (const float*)(dumpbase + (mh * 2 + nc2) * 2048);
#pragma unroll
            for (int mt = 0; mt < 2; ++mt) {
                f32x4 g = acc[mt] + *(const f32x4*)(dp + (mt * 64 + lane) * 4);
#pragma unroll
                for (int r = 0; r < 4; ++r) {
                    int row = mh * 32 + mt * 16 + q * 4 + r;
                    float cand = g[r] + bbT;
                    cand = cand > 0.f ? cand : 0.f;
                    float a = attd[row * SEQ + t];
                    float hold = auxf[row * 32 + nc2 * 16 + c15];
                    float hn = a * cand + (1.f - a) * hold;
                    auxf[row * 32 + nc2 * 16 + c15] = hn;
                    hscr[row * 32 + nc2 * 16 + c15] = f2bf(hn);
                }
            }
        }
        __syncthreads();   // hscr complete
        if (tid < 256) {   // 4 cgs x 64 rows -> contiguous 4KB
            int c4 = tid >> 6, row = tid & 63;
            u32x4 v = *(const u32x4*)(hscr + row * 32 + c4 * 8);
            size_t chunk = (size_t)((bid * 4 + c4) * 64 + row);
            store_16B_wt((char*)h_tagm + (size_t)((t + 1) & 1) * 131072 + chunk * 16, v);
        }
        flag_light(flags, 320, 32, 320 + bid, (unsigned)(t + 1));
    }

    // dump final h (f32) for FC
    for (int i = tid; i < 2048; i += 512) {
        int row = i >> 5, cl = i & 31;
        h_f32[row * HID + bid * 32 + cl] = auxf[i];
    }
    flag_barrier(flags, 320, 32, 320 + bid, 600u);   // heavy: h_f32 cached-written

    // =============== FC: 2 batch rows per block ===============
    {
        float* fcp = (float*)dumpbase;   // [2 rows][2 halves][128]
        int c = tid & 127, half = (tid >> 7) & 1, rw = tid >> 8;
        const float* hrow = h_f32 + (size_t)(bid * 2 + rw) * HID;
        float s = 0.f;
        for (int k = half * 512; k < half * 512 + 512; ++k)
            s += hrow[k] * fc_w[(size_t)k * COUT + c];
        fcp[(rw * 2 + half) * 128 + c] = s;
        __syncthreads();
        if (tid < 256) {
            int rr = tid >> 7, cc = tid & 127;
            out[(bid * 2 + rr) * COUT + cc] = fcp[(rr * 2) * 128 + cc]
                                            + fcp[(rr * 2 + 1) * 128 + cc] + fc_b[cc];
        }
    }
}

extern "C" void kernel_launch(void* const* d_in, const int* in_sizes, int n_in,
                              void* d_out, int out_size, void* d_ws, size_t ws_size,
                              hipStream_t stream) {
    const float* x          = (const float*)d_in[0];
    const float* i2h_w      = (const float*)d_in[1];
    const float* i2h_b      = (const float*)d_in[2];
    const float* h2h_w      = (const float*)d_in[3];
    const float* h2h_b      = (const float*)d_in[4];
    const float* fc_w       = (const float*)d_in[5];
    const float* fc_b       = (const float*)d_in[6];
    const float* att_wi_fwd = (const float*)d_in[7];
    const float* att_wh_fwd = (const float*)d_in[8];
    const float* att_b_fwd  = (const float*)d_in[9];
    const float* att_wi_bwd = (const float*)d_in[10];
    const float* att_wh_bwd = (const float*)d_in[11];
    const float* att_b_bwd  = (const float*)d_in[12];
    const float* att_fc_w   = (const float*)d_in[13];
    const float* att_fc_b   = (const float*)d_in[14];
    float* out = (float*)d_out;

    char* ws = (char*)d_ws;
    // setup-phase (dead after packs)
    unsigned short* WfT = (unsigned short*)(ws + 0);          // 10485760
    unsigned short* WbT = (unsigned short*)(ws + 10485760);   // 10485760
    unsigned short* WtT = (unsigned short*)(ws + 20971520);   // 2621440 -> 23592960
    // packed fragment weights
    unsigned short* Wfp = (unsigned short*)(ws + 23592960);   // 10485760
    unsigned short* Wbp = (unsigned short*)(ws + 34078720);   // 10485760 -> 44564480
    unsigned short* Wtp = (unsigned short*)(ws + 17829888);   // 2621440 -> 20451328 (survives)
    // runtime region
    unsigned short* xtb    = (unsigned short*)(ws + 0);        // 16777216
    unsigned short* h_lstm = (unsigned short*)(ws + 16777216); // 524288
    unsigned short* h_tagm = (unsigned short*)(ws + 17301504); // 262144
    float*          h_f32  = (float*)(ws + 17563648);          // 262144
    unsigned*       flags  = (unsigned*)(ws + 17825792);       // 4096 -> 17829888
    // att_part ALIASES Wfp/Wbp (weights register-resident after epoch-1 barrier)
    float*          att_part = (float*)(ws + 23592960);        // 33554432 -> 57147392

    transpose_weights<<<20 * (NGATE / 64), 256, 0, stream>>>(att_wi_fwd, att_wh_fwd, WfT, NGATE);
    transpose_weights<<<20 * (NGATE / 64), 256, 0, stream>>>(att_wi_bwd, att_wh_bwd, WbT, NGATE);
    transpose_weights<<<20 * (HID / 64), 256, 0, stream>>>(i2h_w, h2h_w, WtT, HID);
    pack_lstm<<<256, 256, 0, stream>>>(WfT, Wfp);
    pack_lstm<<<256, 256, 0, stream>>>(WbT, Wbp);
    pack_tagm<<<128, 256, 0, stream>>>(WtT, Wtp);
    transpose_x<<<(SEQ * BATCH * DIM + 255) / 256, 256, 0, stream>>>(x, xtb);
    // zero recurrent state + flags every call
    (void)hipMemsetAsync(ws + 16777216, 0, 17829888 - 16777216, stream);

    static const int SMEM_BYTES = 131072 + 16384 + 8192 + 4096;   // 159744
    (void)hipFuncSetAttribute(reinterpret_cast<const void*>(tagm_fused),
                              hipFuncAttributeMaxDynamicSharedMemorySize, SMEM_BYTES);
    tagm_fused<<<128, 512, SMEM_BYTES, stream>>>(
        xtb, Wfp, Wbp, Wtp, att_b_fwd, att_b_bwd, att_fc_w, att_fc_b,
        i2h_b, h2h_b, fc_w, fc_b, h_lstm, h_tagm, h_f32, att_part, flags, out);
}

// Round 10
// 9917.493 us; speedup vs baseline: 1.4900x; 1.3194x over previous
//
#include <hip/hip_runtime.h>
#include <hip/hip_bf16.h>
#include <cstdint>
#include <cstddef>

constexpr int BATCH = 64;
constexpr int SEQ   = 512;
constexpr int DIM   = 256;
constexpr int HID   = 1024;
constexpr int COUT  = 128;
constexpr int KTOT  = DIM + HID;   // 1280
constexpr int NGATE = 4 * HID;     // 4096
constexpr float ATT_SIG_W = 3.0f;

using bf16x8 = __attribute__((ext_vector_type(8))) __bf16;
using f32x4  = __attribute__((ext_vector_type(4))) float;
using u32x4  = __attribute__((ext_vector_type(4))) unsigned int;

__device__ __forceinline__ unsigned short f2bf(float f) {
    union { float f; unsigned u; } v; v.f = f;
    unsigned u = v.u;
    u += 0x7fffu + ((u >> 16) & 1u);
    return (unsigned short)(u >> 16);
}

__device__ __forceinline__ float sigm(float x) { return 1.f / (1.f + __expf(-x)); }

// 16B write-through store (sc0 sc1); payload must be ext_vector_type (reg quad)
__device__ __forceinline__ void store_16B_wt(void* p, u32x4 v) {
    asm volatile("global_store_dwordx4 %0, %1, off sc0 sc1"
                 :: "v"(p), "v"(v) : "memory");
}

// global->LDS direct copy, 16B/lane, sc0|sc1 (aux=17): bypass L1+L2, read coherent L3
#define GLOAD_LDS_COHERENT(gptr, lptr)                                     \
    __builtin_amdgcn_global_load_lds(                                      \
        (const __attribute__((address_space(1))) void*)(gptr),             \
        (__attribute__((address_space(3))) void*)(lptr), 16, 0, 17)

// ---- weight transpose+convert: out[n][k] = bf16( k<DIM ? wi[k][n] : wh[k-DIM][n] )
__global__ void transpose_weights(const float* __restrict__ wi,
                                  const float* __restrict__ wh,
                                  unsigned short* __restrict__ out, int N) {
    __shared__ float tile[64][65];
    int ntiles = N >> 6;
    int kt = blockIdx.x / ntiles;
    int nt = blockIdx.x % ntiles;
    int k0 = kt << 6, n0 = nt << 6;
    int a = threadIdx.x & 63, g = threadIdx.x >> 6;
#pragma unroll
    for (int p = 0; p < 16; ++p) {
        int kr = p * 4 + g;
        int k = k0 + kr;
        const float* src = (k < DIM) ? (wi + (size_t)k * N) : (wh + (size_t)(k - DIM) * N);
        tile[kr][a] = src[n0 + a];
    }
    __syncthreads();
#pragma unroll
    for (int p = 0; p < 16; ++p) {
        int nr = p * 4 + g;
        out[(size_t)(n0 + nr) * KTOT + (k0 + a)] = f2bf(tile[a][nr]);
    }
}

// ---- x [B][T][D] f32 -> xt [T][B][D] bf16
__global__ void transpose_x(const float* __restrict__ x, unsigned short* __restrict__ xt) {
    size_t idx = (size_t)blockIdx.x * blockDim.x + threadIdx.x;
    if (idx >= (size_t)SEQ * BATCH * DIM) return;
    int d = idx % DIM;
    size_t r = idx / DIM;
    int b = r % BATCH;
    int t = r / BATCH;
    xt[idx] = f2bf(x[((size_t)b * SEQ + t) * DIM + d]);
}

// ---- pack LSTM weights into per-(colgroup, khalf) MFMA fragment order.
__global__ void pack_lstm(const unsigned short* __restrict__ WT,
                          unsigned short* __restrict__ out) {
    int cg = blockIdx.x >> 1, kh = blockIdx.x & 1;
    size_t base = (size_t)blockIdx.x * 20480;
#pragma unroll
    for (int j = 0; j < 80; ++j) {
        int idx = threadIdx.x * 80 + j;
        int frag = idx >> 9;
        int rem = idx & 511;
        int lane = rem >> 3, e = rem & 7;
        int nt = frag / 20, ksl = frag % 20;
        int p = nt * 16 + (lane & 15);
        int origcol = (p >> 3) * 1024 + cg * 8 + (p & 7);
        int k = kh * 640 + ksl * 32 + ((lane >> 4) & 3) * 8 + e;
        out[base + idx] = WT[(size_t)origcol * KTOT + k];
    }
}

// ---- pack TAGM weights: region (cg,kh): 20 frags x 1024B; col = cg*16+(lane&15)
__global__ void pack_tagm(const unsigned short* __restrict__ WT,
                          unsigned short* __restrict__ out) {
    int cg = blockIdx.x >> 1, kh = blockIdx.x & 1;
    size_t base = (size_t)blockIdx.x * 10240;
#pragma unroll
    for (int j = 0; j < 40; ++j) {
        int idx = threadIdx.x * 40 + j;
        int ksl = idx >> 9;
        int rem = idx & 511;
        int lane = rem >> 3, e = rem & 7;
        int origcol = cg * 16 + (lane & 15);
        int k = kh * 640 + ksl * 32 + ((lane >> 4) & 3) * 8 + e;
        out[base + idx] = WT[(size_t)origcol * KTOT + k];
    }
}

// ---- LIGHT per-step barrier: no cache-maintenance fences (h is WT + L2-bypass)
__device__ __forceinline__ void flag_light(unsigned* flags, int base, int cnt,
                                           int myidx, unsigned epoch) {
    asm volatile("s_waitcnt vmcnt(0)" ::: "memory");  // drain own WT stores
    __syncthreads();
    if (threadIdx.x == 0)
        __hip_atomic_store(flags + myidx, epoch, __ATOMIC_RELAXED, __HIP_MEMORY_SCOPE_AGENT);
    if (threadIdx.x < 64) {
        for (;;) {
            bool ok = true;
            for (int j = (int)threadIdx.x; j < cnt; j += 64)
                ok &= (__hip_atomic_load(flags + base + j, __ATOMIC_RELAXED,
                                         __HIP_MEMORY_SCOPE_AGENT) >= epoch);
            if (__all(ok)) break;
            __builtin_amdgcn_s_sleep(1);
        }
    }
    __syncthreads();
}

// ---- HEAVY barrier (phase boundaries only): full release/acquire fences
__device__ __forceinline__ void flag_barrier(unsigned* flags, int base, int cnt,
                                             int myidx, unsigned epoch) {
    __syncthreads();
    if (threadIdx.x == 0) {
        __builtin_amdgcn_fence(__ATOMIC_RELEASE, "agent");   // wbl2
        __hip_atomic_store(flags + myidx, epoch, __ATOMIC_RELAXED, __HIP_MEMORY_SCOPE_AGENT);
    }
    if (threadIdx.x < 64) {
        for (;;) {
            bool ok = true;
            for (int j = (int)threadIdx.x; j < cnt; j += 64)
                ok &= (__hip_atomic_load(flags + base + j, __ATOMIC_RELAXED,
                                         __HIP_MEMORY_SCOPE_AGENT) >= epoch);
            if (__all(ok)) break;
            __builtin_amdgcn_s_sleep(1);
        }
        if (threadIdx.x == 0)
            __builtin_amdgcn_fence(__ATOMIC_ACQUIRE, "agent");   // inv
    }
    __syncthreads();
}

// ======== persistent fused kernel ========
// grid 256 x 256thr (R4 geometry: VGPR ~240-256, NO spill — R7-R9's 512-thr shape
// was capped at 128 VGPR by the allocator and spilled the weight block).
// h global layout BLOCKED: chunk s = cg8*64 + row (cg8 = h_col>>3), 16B/chunk.
// - stage = IDENTITY linear copy (LDS image == global image), fully coalesced
// - h writes = LDS transpose scratch -> 16B full-line WT stores, block-owned lines
// - MFMA h-read: smem + (kcol>>3)*1024 + row*16 (LDS BW floor, no swizzle needed)
// LSTM: block = (dir = bid&1, cg = bid>>1 : 8 h-cols x 4 gates). wave = (mh, kh).
// TAGM (bid<64): 16 h-cols/block.
__global__ __launch_bounds__(256)
void tagm_fused(const unsigned short* __restrict__ xt,
                const unsigned short* __restrict__ Wfp,
                const unsigned short* __restrict__ Wbp,
                const unsigned short* __restrict__ Wtp,
                const float* __restrict__ bias_f, const float* __restrict__ bias_b,
                const float* __restrict__ attw, const float* __restrict__ att_fc_b,
                const float* __restrict__ i2h_b, const float* __restrict__ h2h_b,
                const float* __restrict__ fc_w, const float* __restrict__ fc_b,
                unsigned short* __restrict__ h_lstm,  // [2 dir][2 buf] x 128KB blocked
                unsigned short* __restrict__ h_tagm,  // [2 buf] x 128KB blocked
                float* __restrict__ h_f32,            // [64][1024]
                float* __restrict__ att_part,         // [256 blk][512*64] f32 (aliases Wfp/Wbp!)
                unsigned* __restrict__ flags,         // [640]
                float* __restrict__ out) {
    extern __shared__ char smem[];                   // [0,131072): blocked h image
    char* dumpbase = smem + 131072;                  // 8 KB acc dump
    float* auxf = (float*)(smem + 131072 + 8192);    // 4 KB: LSTM c / TAGM h master
    unsigned short* hscr = (unsigned short*)(smem + 131072 + 8192 + 4096);  // 2 KB

    int tid = threadIdx.x;
    int wave = tid >> 6, lane = tid & 63;
    int bid = blockIdx.x;
    int dir = bid & 1, cg = bid >> 1;
    int mh = wave >> 1, kh = wave & 1;
    int q = lane >> 4, c15 = lane & 15;

    // ---- LSTM weight fragments -> registers
    bf16x8 wreg[40];
    {
        const unsigned short* wp = (dir ? Wbp : Wfp) + (size_t)(cg * 2 + kh) * 20480;
#pragma unroll
        for (int f = 0; f < 40; ++f)
            wreg[f] = *(const bf16x8*)(wp + f * 512 + lane * 8);
    }
    int hc = lane & 7;
    int colE = cg * 8 + hc;
    const float* bias = dir ? bias_b : bias_f;
    float b_ii = bias[colE], b_ff = bias[HID + colE];
    float b_gg = bias[2 * HID + colE], b_oo = bias[3 * HID + colE];
    float attw_l = attw[dir * HID + colE];

    for (int i = tid; i < 512; i += 256) auxf[i] = 0.f;   // c = 0

    // weights in regs (vmcnt-drained by flag_light) before att_part clobbers Wfp/Wbp
    flag_light(flags, 256, 256, 256 + bid, 1u);

    // =============== LSTM loop ===============
    for (int t = 0; t < SEQ; ++t) {
        int tx = dir ? (SEQ - 1 - t) : t;
        {   // stage h_prev -> LDS: identity linear copy of blocked image (coalesced)
            const char* hsrc = (const char*)h_lstm + (size_t)(dir * 2 + (t & 1)) * 131072;
            char* lbase = smem + (size_t)(tid & 192) * 16;
#pragma unroll
            for (int i = 0; i < 32; ++i) {
                int s = i * 256 + tid;                 // chunk index == LDS chunk index
                GLOAD_LDS_COHERENT(hsrc + (size_t)s * 16, lbase + (size_t)i * 4096);
            }
        }
        // prefetch x fragments (normal cached loads; xt read-only, L2-resident)
        const unsigned short* xrow = xt + (size_t)tx * BATCH * DIM;
        bf16x8 xa[16];
        if (kh == 0) {
#pragma unroll
            for (int ksl = 0; ksl < 8; ++ksl)
#pragma unroll
                for (int mt = 0; mt < 2; ++mt) {
                    int row = mh * 32 + mt * 16 + c15;
                    xa[ksl * 2 + mt] = *(const bf16x8*)(xrow + row * DIM + ksl * 32 + q * 8);
                }
        }
        __syncthreads();   // drains global_load_lds (vmcnt) + xa, then barrier

        f32x4 acc[2][2] = {};
#pragma unroll
        for (int ksl = 0; ksl < 20; ++ksl) {
#pragma unroll
            for (int mt = 0; mt < 2; ++mt) {
                int row = mh * 32 + mt * 16 + c15;
                bf16x8 a;
                if (kh == 0 && ksl < 8) {
                    a = xa[ksl * 2 + mt];
                } else {
                    int kcol = kh * 640 + ksl * 32 + q * 8 - 256;   // h column
                    a = *(const bf16x8*)(smem + (size_t)(kcol >> 3) * 1024 + (size_t)row * 16);
                }
                acc[mt][0] = __builtin_amdgcn_mfma_f32_16x16x32_bf16(a, wreg[ksl],      acc[mt][0], 0, 0, 0);
                acc[mt][1] = __builtin_amdgcn_mfma_f32_16x16x32_bf16(a, wreg[20 + ksl], acc[mt][1], 0, 0, 0);
            }
        }
        if (kh == 1) {   // k-half-1 waves dump partials
            float* dp = (float*)(dumpbase + mh * 4096);
#pragma unroll
            for (int mt = 0; mt < 2; ++mt)
#pragma unroll
                for (int nt = 0; nt < 2; ++nt)
                    *(f32x4*)(dp + ((mt * 2 + nt) * 64 + lane) * 4) = acc[mt][nt];
        }
        __syncthreads();
        if (kh == 0) {   // reduce + gates + state update (waves 0,2 in parallel)
            const float* dp = (const float*)(dumpbase + mh * 4096);
            bool low = (lane & 8) == 0;
#pragma unroll
            for (int mt = 0; mt < 2; ++mt) {
                f32x4 g0 = acc[mt][0] + *(const f32x4*)(dp + ((mt * 2 + 0) * 64 + lane) * 4);
                f32x4 g1 = acc[mt][1] + *(const f32x4*)(dp + ((mt * 2 + 1) * 64 + lane) * 4);
                f32x4 av4;
#pragma unroll
                for (int r = 0; r < 4; ++r) {
                    float fo0 = __shfl(g0[r], lane ^ 8);   // f gate from partner lane
                    float fo1 = __shfl(g1[r], lane ^ 8);   // o gate from partner lane
                    int row = mh * 32 + mt * 16 + q * 4 + r;
                    float si = sigm(g0[r] + b_ii);
                    float sf = sigm(fo0 + b_ff);
                    float tg = tanhf(g1[r] + b_gg);
                    float so = sigm(fo1 + b_oo);
                    float cprev = auxf[row * 8 + hc];
                    float cn = sf * cprev + si * tg;
                    float hn = so * tanhf(cn);
                    float av = low ? hn * attw_l : 0.f;
                    av += __shfl_xor(av, 1); av += __shfl_xor(av, 2); av += __shfl_xor(av, 4);
                    av4[r] = av;
                    if (low) {
                        auxf[row * 8 + hc] = cn;
                        hscr[row * 8 + hc] = f2bf(hn);     // LDS transpose staging
                    }
                }
                if (c15 == 0)
                    *(f32x4*)(att_part + (size_t)bid * 32768 + tx * 64 + (mh * 32 + mt * 16 + q * 4)) = av4;
            }
        }
        __syncthreads();   // hscr complete
        if (tid < 64) {    // block's 1KB region = chunks cg*64..cg*64+63: 16 full lines
            u32x4 v = *(const u32x4*)(hscr + tid * 8);
            store_16B_wt((char*)h_lstm + (size_t)(dir * 2 + ((t + 1) & 1)) * 131072
                         + (size_t)(cg * 64 + tid) * 16, v);
        }
        flag_light(flags, dir * 128, 128, dir * 128 + cg, (unsigned)(t + 1));
    }

    // =============== attention finalize ===============
    flag_barrier(flags, 256, 256, 256 + bid, 2u);   // heavy: att_part cached-written
    {
        int i = tid & 127, half = tid >> 7;
        int item = bid * 128 + i;               // = t*64 + row
        int tt = item >> 6, row = item & 63;
        float s = 0.f;
        const float* p = att_part + (size_t)half * 128 * 32768 + item;
        for (int blk = 0; blk < 128; ++blk)
            s += p[(size_t)blk * 32768];
        float* red = (float*)dumpbase;
        if (half) red[i] = s;
        __syncthreads();
        if (!half)
            out[BATCH * COUT + row * SEQ + tt] = sigm(ATT_SIG_W * (s + red[i] + att_fc_b[0]));
    }
    flag_barrier(flags, 256, 256, 256 + bid, 3u);   // heavy: att out cached-written
    if (bid >= 64) return;

    // =============== TAGM loop (64 blocks x 16 h-cols) ===============
    bf16x8 wt[20];
    {
        const unsigned short* wp = Wtp + (size_t)(bid * 2 + kh) * 10240;
#pragma unroll
        for (int f = 0; f < 20; ++f)
            wt[f] = *(const bf16x8*)(wp + f * 512 + lane * 8);
    }
    int colT = bid * 16 + c15;
    float bbT = i2h_b[colT] + h2h_b[colT];
    for (int i = tid; i < 1024; i += 256) auxf[i] = 0.f;   // h master [64][16]
    __syncthreads();
    const float* attd = out + BATCH * COUT;

    for (int t = 0; t < SEQ; ++t) {
        {   // stage: identity linear copy of blocked image
            const char* hsrc = (const char*)h_tagm + (size_t)(t & 1) * 131072;
            char* lbase = smem + (size_t)(tid & 192) * 16;
#pragma unroll
            for (int i = 0; i < 32; ++i) {
                int s = i * 256 + tid;
                GLOAD_LDS_COHERENT(hsrc + (size_t)s * 16, lbase + (size_t)i * 4096);
            }
        }
        const unsigned short* xrow = xt + (size_t)t * BATCH * DIM;
        bf16x8 xa[16];
        if (kh == 0) {
#pragma unroll
            for (int ksl = 0; ksl < 8; ++ksl)
#pragma unroll
                for (int mt = 0; mt < 2; ++mt) {
                    int row = mh * 32 + mt * 16 + c15;
                    xa[ksl * 2 + mt] = *(const bf16x8*)(xrow + row * DIM + ksl * 32 + q * 8);
                }
        }
        __syncthreads();
        f32x4 acc[2] = {};
#pragma unroll
        for (int ksl = 0; ksl < 20; ++ksl) {
#pragma unroll
            for (int mt = 0; mt < 2; ++mt) {
                int row = mh * 32 + mt * 16 + c15;
                bf16x8 a;
                if (kh == 0 && ksl < 8) {
                    a = xa[ksl * 2 + mt];
                } else {
                    int kcol = kh * 640 + ksl * 32 + q * 8 - 256;
                    a = *(const bf16x8*)(smem + (size_t)(kcol >> 3) * 1024 + (size_t)row * 16);
                }
                acc[mt] = __builtin_amdgcn_mfma_f32_16x16x32_bf16(a, wt[ksl], acc[mt], 0, 0, 0);
            }
        }
        if (kh == 1) {
            float* dp = (float*)(dumpbase + mh * 2048);
            *(f32x4*)(dp + (0 * 64 + lane) * 4) = acc[0];
            *(f32x4*)(dp + (1 * 64 + lane) * 4) = acc[1];
        }
        __syncthreads();
        if (kh == 0) {
            const float* dp = (const float*)(dumpbase + mh * 2048);
#pragma unroll
            for (int mt = 0; mt < 2; ++mt) {
                f32x4 g = acc[mt] + *(const f32x4*)(dp + (mt * 64 + lane) * 4);
#pragma unroll
                for (int r = 0; r < 4; ++r) {
                    int row = mh * 32 + mt * 16 + q * 4 + r;
                    float cand = g[r] + bbT;
                    cand = cand > 0.f ? cand : 0.f;
                    float a = attd[row * SEQ + t];
                    float hold = auxf[row * 16 + c15];
                    float hn = a * cand + (1.f - a) * hold;
                    auxf[row * 16 + c15] = hn;
                    hscr[row * 16 + c15] = f2bf(hn);     // LDS transpose staging
                }
            }
        }
        __syncthreads();   // hscr complete
        if (tid < 128) {   // chunks (bid*2+nn)*64+row: 32 full lines, block-owned
            int nn = tid >> 6, row = tid & 63;
            u32x4 v = *(const u32x4*)(hscr + row * 16 + nn * 8);
            store_16B_wt((char*)h_tagm + (size_t)((t + 1) & 1) * 131072
                         + (size_t)((bid * 2 + nn) * 64 + row) * 16, v);
        }
        flag_light(flags, 512, 64, 512 + bid, (unsigned)(t + 1));
    }

    // dump final h (f32) for FC
    for (int i = tid; i < 1024; i += 256) {
        int row = i >> 4, cl = i & 15;
        h_f32[row * HID + bid * 16 + cl] = auxf[i];
    }
    flag_barrier(flags, 576, 64, 576 + bid, 1u);   // heavy: h_f32 cached-written

    // =============== FC: out[b][c], block = batch row ===============
    {
        float* fcp = (float*)dumpbase;   // [2][128]
        int c = tid & 127, half = tid >> 7;
        const float* hrow = h_f32 + (size_t)bid * HID;
        float s = 0.f;
        for (int k = half * 512; k < half * 512 + 512; ++k)
            s += hrow[k] * fc_w[(size_t)k * COUT + c];
        fcp[half * 128 + c] = s;
        __syncthreads();
        if (tid < 128)
            out[bid * COUT + tid] = fcp[tid] + fcp[128 + tid] + fc_b[tid];
    }
}

extern "C" void kernel_launch(void* const* d_in, const int* in_sizes, int n_in,
                              void* d_out, int out_size, void* d_ws, size_t ws_size,
                              hipStream_t stream) {
    const float* x          = (const float*)d_in[0];
    const float* i2h_w      = (const float*)d_in[1];
    const float* i2h_b      = (const float*)d_in[2];
    const float* h2h_w      = (const float*)d_in[3];
    const float* h2h_b      = (const float*)d_in[4];
    const float* fc_w       = (const float*)d_in[5];
    const float* fc_b       = (const float*)d_in[6];
    const float* att_wi_fwd = (const float*)d_in[7];
    const float* att_wh_fwd = (const float*)d_in[8];
    const float* att_b_fwd  = (const float*)d_in[9];
    const float* att_wi_bwd = (const float*)d_in[10];
    const float* att_wh_bwd = (const float*)d_in[11];
    const float* att_b_bwd  = (const float*)d_in[12];
    const float* att_fc_w   = (const float*)d_in[13];
    const float* att_fc_b   = (const float*)d_in[14];
    float* out = (float*)d_out;

    char* ws = (char*)d_ws;
    // setup-phase (dead after packs)
    unsigned short* WfT = (unsigned short*)(ws + 0);          // 10485760
    unsigned short* WbT = (unsigned short*)(ws + 10485760);   // 10485760
    unsigned short* WtT = (unsigned short*)(ws + 20971520);   // 2621440 -> 23592960
    // packed fragment weights
    unsigned short* Wfp = (unsigned short*)(ws + 23592960);   // 10485760
    unsigned short* Wbp = (unsigned short*)(ws + 34078720);   // 10485760 -> 44564480
    unsigned short* Wtp = (unsigned short*)(ws + 17829888);   // 2621440 -> 20451328 (survives)
    // runtime region
    unsigned short* xtb    = (unsigned short*)(ws + 0);        // 16777216
    unsigned short* h_lstm = (unsigned short*)(ws + 16777216); // 524288
    unsigned short* h_tagm = (unsigned short*)(ws + 17301504); // 262144
    float*          h_f32  = (float*)(ws + 17563648);          // 262144
    unsigned*       flags  = (unsigned*)(ws + 17825792);       // 4096 -> 17829888
    // att_part ALIASES Wfp/Wbp (weights register-resident after epoch-1 barrier)
    float*          att_part = (float*)(ws + 23592960);        // 33554432 -> 57147392

    transpose_weights<<<20 * (NGATE / 64), 256, 0, stream>>>(att_wi_fwd, att_wh_fwd, WfT, NGATE);
    transpose_weights<<<20 * (NGATE / 64), 256, 0, stream>>>(att_wi_bwd, att_wh_bwd, WbT, NGATE);
    transpose_weights<<<20 * (HID / 64), 256, 0, stream>>>(i2h_w, h2h_w, WtT, HID);
    pack_lstm<<<256, 256, 0, stream>>>(WfT, Wfp);
    pack_lstm<<<256, 256, 0, stream>>>(WbT, Wbp);
    pack_tagm<<<128, 256, 0, stream>>>(WtT, Wtp);
    transpose_x<<<(SEQ * BATCH * DIM + 255) / 256, 256, 0, stream>>>(x, xtb);
    // zero recurrent state + flags every call
    (void)hipMemsetAsync(ws + 16777216, 0, 17829888 - 16777216, stream);

    static const int SMEM_BYTES = 131072 + 8192 + 4096 + 2048;   // 145408
    (void)hipFuncSetAttribute(reinterpret_cast<const void*>(tagm_fused),
                              hipFuncAttributeMaxDynamicSharedMemorySize, SMEM_BYTES);
    tagm_fused<<<256, 256, SMEM_BYTES, stream>>>(
        xtb, Wfp, Wbp, Wtp, att_b_fwd, att_b_bwd, att_fc_w, att_fc_b,
        i2h_b, h2h_b, fc_w, fc_b, h_lstm, h_tagm, h_f32, att_part, flags, out);
}